// Round 8
// baseline (207.842 us; speedup 1.0000x reference)
//
#include <hip/hip_runtime.h>

#define TQ 512
#define TK 256
#define BB 8
#define CC 128

// 2*log2(e): exp2(SCALE2L2E * x) == e^(2x)
#define SCALE2L2E 2.8853900817779268f
#define L2E 1.4426950408889634f

__device__ __forceinline__ float fexp2(float x) { return __builtin_amdgcn_exp2f(x); }
__device__ __forceinline__ float frcp(float x)  { return __builtin_amdgcn_rcpf(x); }

// ---------------- projection GEMM v8: no LDS, register pipeline ----------------
// Y(rows x 128) = X(rows x K) @ W(128 x K)^T ; row r -> (t = r/8, b = r%8).
// Block: 16 rows x 128 cols, 256 thr; thread = 2 rows x 4 cols (acc[2][4]).
// X rows broadcast across 32 lanes (L1); W streams 320KB L2-resident with 4x
// line reuse (L1 working set 8KB/k4-group). Depth-4 register pipeline: issue
// stage s for k4+4 right after computing stage s -> ~3 compute phases (384 cy)
// of latency cover. No DS, no barriers.
// EXPOUT: epilogue applies exp2(scale*acc) (energy factorization e^{2q}*e^{2k}).
template<int K, int LAY, int EXPOUT>
__device__ __forceinline__ void proj_body8(
    const float* __restrict__ X, const float* __restrict__ W,
    float* __restrict__ Y, float scale, int Tdim, int tile)
{
    constexpr int NK4 = K / 4;
    constexpr int DEPTH = 4;
    constexpr int NG = NK4 / DEPTH;     // KV: 40, Q: 5

    const int tid = threadIdx.x;
    const int tx = tid & 31;            // col group: cols tx*4..+3
    const int ty = tid >> 5;            // 0..7: rows ty*2, ty*2+1
    const int r0 = tile * 16 + ty * 2;
    const int c0 = tx * 4;

    const float* __restrict__ Xr0 = X + (size_t)r0 * K;
    const float* __restrict__ Xr1 = Xr0 + K;
    const float* __restrict__ Wc0 = W + (size_t)c0 * K;
    const float* __restrict__ Wc1 = Wc0 + K;
    const float* __restrict__ Wc2 = Wc1 + K;
    const float* __restrict__ Wc3 = Wc2 + K;

    float4 xa[DEPTH][2];
    float4 wa[DEPTH][4];
    float acc[2][4];
#pragma unroll
    for (int i = 0; i < 2; ++i)
#pragma unroll
        for (int j = 0; j < 4; ++j) acc[i][j] = 0.f;

#define ISSUE(s, k4)  do {                                   \
        xa[s][0] = *(const float4*)&Xr0[(k4) * 4];           \
        xa[s][1] = *(const float4*)&Xr1[(k4) * 4];           \
        wa[s][0] = *(const float4*)&Wc0[(k4) * 4];           \
        wa[s][1] = *(const float4*)&Wc1[(k4) * 4];           \
        wa[s][2] = *(const float4*)&Wc2[(k4) * 4];           \
        wa[s][3] = *(const float4*)&Wc3[(k4) * 4];           \
    } while (0)

#define COMPUTE(s)  do {                                     \
        _Pragma("unroll")                                    \
        for (int i = 0; i < 2; ++i) {                        \
            _Pragma("unroll")                                \
            for (int j = 0; j < 4; ++j) {                    \
                acc[i][j] = fmaf(xa[s][i].x, wa[s][j].x, acc[i][j]); \
                acc[i][j] = fmaf(xa[s][i].y, wa[s][j].y, acc[i][j]); \
                acc[i][j] = fmaf(xa[s][i].z, wa[s][j].z, acc[i][j]); \
                acc[i][j] = fmaf(xa[s][i].w, wa[s][j].w, acc[i][j]); \
            }                                                \
        }                                                    \
    } while (0)

#pragma unroll
    for (int s = 0; s < DEPTH; ++s) ISSUE(s, s);

    for (int g = 0; g < NG - 1; ++g) {
#pragma unroll
        for (int s = 0; s < DEPTH; ++s) {
            const int k4 = g * DEPTH + s;
            COMPUTE(s);
            ISSUE(s, k4 + DEPTH);
        }
    }
#pragma unroll
    for (int s = 0; s < DEPTH; ++s) COMPUTE(s);

#undef ISSUE
#undef COMPUTE

#pragma unroll
    for (int i = 0; i < 2; ++i) {
        const int r = r0 + i;
        const int t = r >> 3, b = r & 7;
        float v0 = acc[i][0] * scale, v1 = acc[i][1] * scale;
        float v2 = acc[i][2] * scale, v3 = acc[i][3] * scale;
        if (EXPOUT) { v0 = fexp2(v0); v1 = fexp2(v1); v2 = fexp2(v2); v3 = fexp2(v3); }
        if (LAY == 0) {
            *(float4*)&Y[((size_t)b * Tdim + t) * CC + c0] = make_float4(v0, v1, v2, v3);
        } else {
            Y[((size_t)b * CC + c0 + 0) * Tdim + t] = v0;
            Y[((size_t)b * CC + c0 + 1) * Tdim + t] = v1;
            Y[((size_t)b * CC + c0 + 2) * Tdim + t] = v2;
            Y[((size_t)b * CC + c0 + 3) * Tdim + t] = v3;
        }
    }
}

// 512 blocks: odd = Q (256 tiles), even = K (128) then V (128) -> each CU
// hosts one long KV block + one short Q block.
__global__ __launch_bounds__(256) void proj_v8(
    const float* __restrict__ q_in, const float* __restrict__ Wq, float* __restrict__ eqp,
    const float* __restrict__ k_in, const float* __restrict__ Wk, float* __restrict__ ekp,
    const float* __restrict__ v_in, const float* __restrict__ Wv, float* __restrict__ vp)
{
    const int id = blockIdx.x;
    const int idx = id >> 1;
    if (id & 1) {
        proj_body8<80, 0, 1>(q_in, Wq, eqp, SCALE2L2E, TQ, idx);          // Eq = e^{2q}
    } else if (idx < 128) {
        proj_body8<640, 1, 1>(k_in, Wk, ekp, SCALE2L2E, TK, idx);         // Ek = e^{2k}
    } else {
        proj_body8<640, 0, 0>(v_in, Wv, vp, 1.0f, TK, idx - 128);
    }
}

// ---------------- Kernel 2: scores + softmax ----------------
// tanh(q+k) = 1 - 2/(Eq*Ek + 1): 1 TRANS + 3 VALU per element.
// Wave = 2 q-rows x 256 k (lane = k/4 via float4 from L2-resident Ek^T).
// Eq / Wvec via wave-uniform s_loads. No LDS, no barriers.
__global__ __launch_bounds__(256) void attn_kernel(const float* __restrict__ eqp,
                                                   const float* __restrict__ ekp,
                                                   const float* __restrict__ Wvec,
                                                   float* __restrict__ attn_out) {
    const int tid = threadIdx.x;
    const int lane = tid & 63;
    const int w = __builtin_amdgcn_readfirstlane(tid >> 6);
    const int b = blockIdx.y;
    const int q0 = blockIdx.x * 8 + w * 2;

    const float* __restrict__ qr0 = eqp + ((size_t)b * TQ + q0) * CC;
    const float* __restrict__ qr1 = qr0 + CC;
    const float* __restrict__ kb = ekp + (size_t)b * CC * TK + lane * 4;

    float sw = Wvec[lane] + Wvec[64 + lane];
#pragma unroll
    for (int m = 32; m >= 1; m >>= 1) sw += __shfl_xor(sw, m, 64);

    float a0[4] = {0.f, 0.f, 0.f, 0.f};
    float a1[4] = {0.f, 0.f, 0.f, 0.f};

#pragma unroll 8
    for (int c = 0; c < CC; ++c) {
        const float4 kf = *(const float4*)&kb[c * TK];
        const float eqa = qr0[c];    // s_load (uniform)
        const float eqb = qr1[c];    // s_load (uniform)
        const float wc = Wvec[c];    // s_load (uniform)
        a0[0] = fmaf(wc, frcp(fmaf(eqa, kf.x, 1.f)), a0[0]);
        a0[1] = fmaf(wc, frcp(fmaf(eqa, kf.y, 1.f)), a0[1]);
        a0[2] = fmaf(wc, frcp(fmaf(eqa, kf.z, 1.f)), a0[2]);
        a0[3] = fmaf(wc, frcp(fmaf(eqa, kf.w, 1.f)), a0[3]);
        a1[0] = fmaf(wc, frcp(fmaf(eqb, kf.x, 1.f)), a1[0]);
        a1[1] = fmaf(wc, frcp(fmaf(eqb, kf.y, 1.f)), a1[1]);
        a1[2] = fmaf(wc, frcp(fmaf(eqb, kf.z, 1.f)), a1[2]);
        a1[3] = fmaf(wc, frcp(fmaf(eqb, kf.w, 1.f)), a1[3]);
    }

    float sc0[4], sc1[4];
#pragma unroll
    for (int j = 0; j < 4; ++j) {
        sc0[j] = sw - 2.f * a0[j];
        sc1[j] = sw - 2.f * a1[j];
    }

    float m0 = fmaxf(fmaxf(sc0[0], sc0[1]), fmaxf(sc0[2], sc0[3]));
    float m1 = fmaxf(fmaxf(sc1[0], sc1[1]), fmaxf(sc1[2], sc1[3]));
#pragma unroll
    for (int m = 32; m >= 1; m >>= 1) {
        m0 = fmaxf(m0, __shfl_xor(m0, m, 64));
        m1 = fmaxf(m1, __shfl_xor(m1, m, 64));
    }
    float e0[4], e1[4], s0 = 0.f, s1 = 0.f;
#pragma unroll
    for (int j = 0; j < 4; ++j) {
        e0[j] = fexp2((sc0[j] - m0) * L2E); s0 += e0[j];
        e1[j] = fexp2((sc1[j] - m1) * L2E); s1 += e1[j];
    }
#pragma unroll
    for (int m = 32; m >= 1; m >>= 1) {
        s0 += __shfl_xor(s0, m, 64);
        s1 += __shfl_xor(s1, m, 64);
    }
    const float r0 = frcp(s0), r1 = frcp(s1);

    const float4 p0 = make_float4(e0[0] * r0, e0[1] * r0, e0[2] * r0, e0[3] * r0);
    const float4 p1 = make_float4(e1[0] * r1, e1[1] * r1, e1[2] * r1, e1[3] * r1);
    *(float4*)&attn_out[((size_t)b * TQ + q0) * TK + lane * 4] = p0;
    *(float4*)&attn_out[((size_t)b * TQ + q0 + 1) * TK + lane * 4] = p1;
}

// ---------------- Kernel 3: PV ----------------
// out[b][c][q] = sum_k p[b][q][k] * v[b][k][c].
// Thread = c, half-block = 8 q rows; p via wave-uniform s_loads, v coalesced.
__global__ __launch_bounds__(256) void pv_kernel(const float* __restrict__ attn,
                                                 const float* __restrict__ vp,
                                                 float* __restrict__ out) {
    const int tid = threadIdx.x;
    const int c = tid & 127;
    const int qh = __builtin_amdgcn_readfirstlane(tid >> 7);
    const int b = blockIdx.y;
    const int q0 = blockIdx.x * 16 + qh * 8;

    const float* __restrict__ vb = vp + (size_t)b * TK * CC + c;
    const float* __restrict__ p0 = attn + ((size_t)b * TQ + q0) * TK;   // uniform base

    float acc[8];
#pragma unroll
    for (int i = 0; i < 8; ++i) acc[i] = 0.f;

#pragma unroll 4
    for (int k = 0; k < TK; ++k) {
        const float vv = vb[k * CC];
#pragma unroll
        for (int i = 0; i < 8; ++i)
            acc[i] = fmaf(p0[i * TK + k], vv, acc[i]);   // p via s_load
    }

#pragma unroll
    for (int i = 0; i < 8; ++i)
        out[((size_t)b * CC + c) * TQ + q0 + i] = acc[i];
}

extern "C" void kernel_launch(void* const* d_in, const int* in_sizes, int n_in,
                              void* d_out, int out_size, void* d_ws, size_t ws_size,
                              hipStream_t stream) {
    const float* queries = (const float*)d_in[0];
    const float* keys    = (const float*)d_in[1];
    const float* values  = (const float*)d_in[2];
    const float* Wq      = (const float*)d_in[3];
    const float* Wk      = (const float*)d_in[4];
    const float* Wv      = (const float*)d_in[5];
    const float* Wvec    = (const float*)d_in[6];

    float* out  = (float*)d_out;                 // (8,128,512)
    float* attn = out + BB * CC * TQ;            // (8,512,256)

    float* ws = (float*)d_ws;
    float* eqp = ws;                   // [b][t][c] 4096*128, e^{2q}
    float* ekp = eqp + 4096 * CC;      // [b][c][t] 2048*128, e^{2k}
    float* vp  = ekp + 2048 * CC;      // [b][t][c] 2048*128

    proj_v8<<<dim3(512), 256, 0, stream>>>(
        queries, Wq, eqp, keys, Wk, ekp, values, Wv, vp);
    attn_kernel<<<dim3(64, 8), 256, 0, stream>>>(eqp, ekp, Wvec, attn);
    pv_kernel<<<dim3(32, 8), 256, 0, stream>>>(attn, vp, out);
}

// Round 9
// 74.148 us; speedup vs baseline: 2.8031x; 2.8031x over previous
//
#include <hip/hip_runtime.h>

#define TQ 512
#define TK 256
#define BB 8
#define CC 128

// 2*log2(e): exp2(SCALE2L2E * x) == e^(2x)
#define SCALE2L2E 2.8853900817779268f
#define L2E 1.4426950408889634f

__device__ __forceinline__ float fexp2(float x) { return __builtin_amdgcn_exp2f(x); }
__device__ __forceinline__ float frcp(float x)  { return __builtin_amdgcn_rcpf(x); }

// ---------------- projection GEMM (round-4 proj2 structure, measured-good) ----
// Y(rows x 128) = X(rows x K) @ W(128 x K)^T ; row r -> (t = r/8, b = r%8).
// Block: 16 rows x 128 cols, 256 thr; thread = 2 rows x 4 cols (acc[2][4]).
// Register-prefetch: chunk kc+1 global loads issued right after LDS publish of
// chunk kc. Single LDS buffer, 2 barriers/chunk.
// EXPO: epilogue applies exp2(scale*acc) (energy factorization e^{2q}*e^{2k}).
template<int K, int KC, int LAY, int EXPO>
__device__ __forceinline__ void proj_tile4(
    const float* __restrict__ X, const float* __restrict__ W,
    float* __restrict__ Y, float scale, int Tdim, int tile, float* lds)
{
    constexpr int NCH = K / KC;
    constexpr int KC4 = KC / 4;
    constexpr int WROW = 132;
    constexpr int XPAD = KC + 4;
    constexpr int NXJ = 16 * KC4;               // X float4 jobs
    constexpr int NWJ = (128 * KC4) / 256;      // W float4 jobs per thread

    float* ws = lds;                 // [KC][WROW]  (W^T chunk)
    float* xs = lds + KC * WROW;     // [16][XPAD]

    const int tid = threadIdx.x;
    const int r0 = tile * 16;

    const int xr = tid / KC4, xj = tid % KC4;

    float4 px;
    float4 pw[NWJ];

    auto issue = [&](int kc) {
        if (tid < NXJ)
            px = *(const float4*)&X[(size_t)(r0 + xr) * K + kc * KC + xj * 4];
#pragma unroll
        for (int m = 0; m < NWJ; ++m) {
            int i = tid + 256 * m;
            int c = i / KC4, j = i % KC4;
            pw[m] = *(const float4*)&W[(size_t)c * K + kc * KC + j * 4];
        }
    };

    issue(0);

    const int rg = tid >> 5;          // 0..7 -> rows rg*2, rg*2+1
    const int c4 = (tid & 31) * 4;    // 0,4,...,124

    float acc[2][4];
#pragma unroll
    for (int i = 0; i < 2; ++i)
#pragma unroll
        for (int j = 0; j < 4; ++j) acc[i][j] = 0.f;

    for (int kc = 0; kc < NCH; ++kc) {
        if (kc) __syncthreads();                 // prev-chunk readers done
        if (tid < NXJ)
            *(float4*)&xs[xr * XPAD + xj * 4] = px;
#pragma unroll
        for (int m = 0; m < NWJ; ++m) {
            int i = tid + 256 * m;
            int c = i / KC4, j = i % KC4;
            ws[(j * 4 + 0) * WROW + c] = pw[m].x;
            ws[(j * 4 + 1) * WROW + c] = pw[m].y;
            ws[(j * 4 + 2) * WROW + c] = pw[m].z;
            ws[(j * 4 + 3) * WROW + c] = pw[m].w;
        }
        __syncthreads();
        if (kc + 1 < NCH) issue(kc + 1);         // in flight under compute

#pragma unroll
        for (int k4 = 0; k4 < KC4; ++k4) {
            float4 wv[4];
            float4 xv[2];
#pragma unroll
            for (int m = 0; m < 4; ++m)
                wv[m] = *(const float4*)&ws[(k4 * 4 + m) * WROW + c4];
#pragma unroll
            for (int i = 0; i < 2; ++i)
                xv[i] = *(const float4*)&xs[(rg * 2 + i) * XPAD + k4 * 4];
#pragma unroll
            for (int i = 0; i < 2; ++i) {
                const float xa[4] = {xv[i].x, xv[i].y, xv[i].z, xv[i].w};
#pragma unroll
                for (int m = 0; m < 4; ++m) {
                    acc[i][0] = fmaf(xa[m], wv[m].x, acc[i][0]);
                    acc[i][1] = fmaf(xa[m], wv[m].y, acc[i][1]);
                    acc[i][2] = fmaf(xa[m], wv[m].z, acc[i][2]);
                    acc[i][3] = fmaf(xa[m], wv[m].w, acc[i][3]);
                }
            }
        }
    }

#pragma unroll
    for (int i = 0; i < 2; ++i) {
        int grow = r0 + rg * 2 + i;
        int t = grow >> 3, b = grow & 7;
        float v0 = acc[i][0] * scale, v1 = acc[i][1] * scale;
        float v2 = acc[i][2] * scale, v3 = acc[i][3] * scale;
        if (EXPO) { v0 = fexp2(v0); v1 = fexp2(v1); v2 = fexp2(v2); v3 = fexp2(v3); }
        if (LAY == 0) {
            *(float4*)&Y[((size_t)b * Tdim + t) * CC + c4] = make_float4(v0, v1, v2, v3);
        } else {
            Y[((size_t)b * CC + c4 + 0) * Tdim + t] = v0;
            Y[((size_t)b * CC + c4 + 1) * Tdim + t] = v1;
            Y[((size_t)b * CC + c4 + 2) * Tdim + t] = v2;
            Y[((size_t)b * CC + c4 + 3) * Tdim + t] = v3;
        }
    }
}

// One merged dispatch: y=0 -> K (x<128) / V (x>=128); y=1 -> Q. 512 blocks.
__global__ __launch_bounds__(256) void proj_all4(
    const float* __restrict__ q_in, const float* __restrict__ Wq, float* __restrict__ eqp,
    const float* __restrict__ k_in, const float* __restrict__ Wk, float* __restrict__ ekp,
    const float* __restrict__ v_in, const float* __restrict__ Wv, float* __restrict__ vp)
{
    __shared__ float lds[40 * 132 + 16 * 44];    // max(Q, KV) footprint
    if (blockIdx.y == 1) {
        proj_tile4<80, 40, 0, 1>(q_in, Wq, eqp, SCALE2L2E, TQ, blockIdx.x, lds);       // Eq=e^{2q}
    } else if ((int)blockIdx.x < 128) {
        proj_tile4<640, 32, 1, 1>(k_in, Wk, ekp, SCALE2L2E, TK, blockIdx.x, lds);      // Ek=e^{2k}, [b][c][t]
    } else {
        proj_tile4<640, 32, 0, 0>(v_in, Wv, vp, 1.0f, TK, blockIdx.x - 128, lds);
    }
}

// ---------------- Kernel 2: scores + softmax ----------------
// tanh(q+k) = 1 - 2/(Eq*Ek + 1): 1 TRANS + 2 VALU per element.
// Wave = 2 q-rows x 256 k (lane = k/4 via float4 from L2-resident Ek^T).
// Eq / Wvec via wave-uniform s_loads. No LDS, no barriers.
__global__ __launch_bounds__(256) void attn_kernel(const float* __restrict__ eqp,
                                                   const float* __restrict__ ekp,
                                                   const float* __restrict__ Wvec,
                                                   float* __restrict__ attn_out) {
    const int tid = threadIdx.x;
    const int lane = tid & 63;
    const int w = __builtin_amdgcn_readfirstlane(tid >> 6);
    const int b = blockIdx.y;
    const int q0 = blockIdx.x * 8 + w * 2;

    const float* __restrict__ qr0 = eqp + ((size_t)b * TQ + q0) * CC;
    const float* __restrict__ qr1 = qr0 + CC;
    const float* __restrict__ kb = ekp + (size_t)b * CC * TK + lane * 4;

    float sw = Wvec[lane] + Wvec[64 + lane];
#pragma unroll
    for (int m = 32; m >= 1; m >>= 1) sw += __shfl_xor(sw, m, 64);

    float a0[4] = {0.f, 0.f, 0.f, 0.f};
    float a1[4] = {0.f, 0.f, 0.f, 0.f};

#pragma unroll 8
    for (int c = 0; c < CC; ++c) {
        const float4 kf = *(const float4*)&kb[c * TK];
        const float eqa = qr0[c];    // s_load (uniform)
        const float eqb = qr1[c];    // s_load (uniform)
        const float wc = Wvec[c];    // s_load (uniform)
        a0[0] = fmaf(wc, frcp(fmaf(eqa, kf.x, 1.f)), a0[0]);
        a0[1] = fmaf(wc, frcp(fmaf(eqa, kf.y, 1.f)), a0[1]);
        a0[2] = fmaf(wc, frcp(fmaf(eqa, kf.z, 1.f)), a0[2]);
        a0[3] = fmaf(wc, frcp(fmaf(eqa, kf.w, 1.f)), a0[3]);
        a1[0] = fmaf(wc, frcp(fmaf(eqb, kf.x, 1.f)), a1[0]);
        a1[1] = fmaf(wc, frcp(fmaf(eqb, kf.y, 1.f)), a1[1]);
        a1[2] = fmaf(wc, frcp(fmaf(eqb, kf.z, 1.f)), a1[2]);
        a1[3] = fmaf(wc, frcp(fmaf(eqb, kf.w, 1.f)), a1[3]);
    }

    float sc0[4], sc1[4];
#pragma unroll
    for (int j = 0; j < 4; ++j) {
        sc0[j] = sw - 2.f * a0[j];
        sc1[j] = sw - 2.f * a1[j];
    }

    float m0 = fmaxf(fmaxf(sc0[0], sc0[1]), fmaxf(sc0[2], sc0[3]));
    float m1 = fmaxf(fmaxf(sc1[0], sc1[1]), fmaxf(sc1[2], sc1[3]));
#pragma unroll
    for (int m = 32; m >= 1; m >>= 1) {
        m0 = fmaxf(m0, __shfl_xor(m0, m, 64));
        m1 = fmaxf(m1, __shfl_xor(m1, m, 64));
    }
    float e0[4], e1[4], s0 = 0.f, s1 = 0.f;
#pragma unroll
    for (int j = 0; j < 4; ++j) {
        e0[j] = fexp2((sc0[j] - m0) * L2E); s0 += e0[j];
        e1[j] = fexp2((sc1[j] - m1) * L2E); s1 += e1[j];
    }
#pragma unroll
    for (int m = 32; m >= 1; m >>= 1) {
        s0 += __shfl_xor(s0, m, 64);
        s1 += __shfl_xor(s1, m, 64);
    }
    const float r0 = frcp(s0), r1 = frcp(s1);

    const float4 p0 = make_float4(e0[0] * r0, e0[1] * r0, e0[2] * r0, e0[3] * r0);
    const float4 p1 = make_float4(e1[0] * r1, e1[1] * r1, e1[2] * r1, e1[3] * r1);
    *(float4*)&attn_out[((size_t)b * TQ + q0) * TK + lane * 4] = p0;
    *(float4*)&attn_out[((size_t)b * TQ + q0 + 1) * TK + lane * 4] = p1;
}

// ---------------- Kernel 3: PV ----------------
// out[b][c][q] = sum_k p[b][q][k] * v[b][k][c].
// Thread = c, half-block = 8 q rows; p via wave-uniform s_loads, v coalesced.
__global__ __launch_bounds__(256) void pv_kernel(const float* __restrict__ attn,
                                                 const float* __restrict__ vp,
                                                 float* __restrict__ out) {
    const int tid = threadIdx.x;
    const int c = tid & 127;
    const int qh = __builtin_amdgcn_readfirstlane(tid >> 7);
    const int b = blockIdx.y;
    const int q0 = blockIdx.x * 16 + qh * 8;

    const float* __restrict__ vb = vp + (size_t)b * TK * CC + c;
    const float* __restrict__ p0 = attn + ((size_t)b * TQ + q0) * TK;   // uniform base

    float acc[8];
#pragma unroll
    for (int i = 0; i < 8; ++i) acc[i] = 0.f;

#pragma unroll 4
    for (int k = 0; k < TK; ++k) {
        const float vv = vb[k * CC];
#pragma unroll
        for (int i = 0; i < 8; ++i)
            acc[i] = fmaf(p0[i * TK + k], vv, acc[i]);   // p via s_load
    }

#pragma unroll
    for (int i = 0; i < 8; ++i)
        out[((size_t)b * CC + c) * TQ + q0 + i] = acc[i];
}

extern "C" void kernel_launch(void* const* d_in, const int* in_sizes, int n_in,
                              void* d_out, int out_size, void* d_ws, size_t ws_size,
                              hipStream_t stream) {
    const float* queries = (const float*)d_in[0];
    const float* keys    = (const float*)d_in[1];
    const float* values  = (const float*)d_in[2];
    const float* Wq      = (const float*)d_in[3];
    const float* Wk      = (const float*)d_in[4];
    const float* Wv      = (const float*)d_in[5];
    const float* Wvec    = (const float*)d_in[6];

    float* out  = (float*)d_out;                 // (8,128,512)
    float* attn = out + BB * CC * TQ;            // (8,512,256)

    float* ws = (float*)d_ws;
    float* eqp = ws;                   // [b][t][c] 4096*128, e^{2q}
    float* ekp = eqp + 4096 * CC;      // [b][c][t] 2048*128, e^{2k}
    float* vp  = ekp + 2048 * CC;      // [b][t][c] 2048*128

    proj_all4<<<dim3(256, 2), 256, 0, stream>>>(
        queries, Wq, eqp, keys, Wk, ekp, values, Wv, vp);
    attn_kernel<<<dim3(64, 8), 256, 0, stream>>>(eqp, ekp, Wvec, attn);
    pv_kernel<<<dim3(32, 8), 256, 0, stream>>>(attn, vp, out);
}

// Round 11
// 64.580 us; speedup vs baseline: 3.2184x; 1.1482x over previous
//
#include <hip/hip_runtime.h>

#define TQ 512
#define TK 256
#define BB 8
#define CC 128

// 2*log2(e): exp2(SCALE2L2E * x) == e^(2x)
#define SCALE2L2E 2.8853900817779268f
#define L2E 1.4426950408889634f

__device__ __forceinline__ float fexp2(float x) { return __builtin_amdgcn_exp2f(x); }
__device__ __forceinline__ float frcp(float x)  { return __builtin_amdgcn_rcpf(x); }

typedef __fp16 h16x2 __attribute__((ext_vector_type(2)));
typedef _Float16 f16x8 __attribute__((ext_vector_type(8)));
typedef float f32x4 __attribute__((ext_vector_type(4)));

union F16x8U { f16x8 v; h16x2 h[4]; };

// ---------------- Kernel 0: fp32 -> fp16 convert (W's + Xq, K-padded) -------
// Wk,Wv: [128][640] -> same layout fp16. Wq: [128][80] -> [128][96] pad0.
// Xq: rows 4096 x 80 -> [4096][96] pad0.
#define NWK 81920
#define NWV 81920
#define NWQ 12288
#define NXQ 393216
#define NCONV (NWK + NWV + NWQ + NXQ)

__global__ __launch_bounds__(256) void convert_kernel(
    const float* __restrict__ Wk, const float* __restrict__ Wv,
    const float* __restrict__ Wq, const float* __restrict__ q_in,
    _Float16* __restrict__ Wk16, _Float16* __restrict__ Wv16,
    _Float16* __restrict__ Wq16, _Float16* __restrict__ Xq16)
{
    for (int i = blockIdx.x * 256 + threadIdx.x; i < NCONV; i += gridDim.x * 256) {
        if (i < NWK) {
            Wk16[i] = (_Float16)Wk[i];
        } else if (i < NWK + NWV) {
            int j = i - NWK;
            Wv16[j] = (_Float16)Wv[j];
        } else if (i < NWK + NWV + NWQ) {
            int j = i - NWK - NWV;
            int c = j / 96, k = j % 96;
            Wq16[j] = (k < 80) ? (_Float16)Wq[c * 80 + k] : (_Float16)0.f;
        } else {
            int j = i - NWK - NWV - NWQ;
            int r = j / 96, k = j % 96;
            Xq16[j] = (k < 80) ? (_Float16)q_in[r * 80 + k] : (_Float16)0.f;
        }
    }
}

// ---------------- Kernel 1: MFMA projections ----------------
// Y(rows x 128) = X(rows x K) @ W(128 x K)^T ; row r -> (t = r/8, b = r%8).
// mfma_f32_16x16x32_f16. Wave = 16 rows x 32 cols (2 c-tiles), no LDS:
//  A-frag: lane l = X[r0 + (l&15)][k0 + (l>>4)*8 ..+7]  (16B contiguous)
//  B-frag: lane l = W[c0 + (l&15)][k0 + (l>>4)*8 ..+7]  (16B contiguous, L1-hot)
//  D: lane l, reg j -> row r0+(l>>4)*4+j, col c0+(l&15)   [verified layout]
// KV A-frags converted in-register from fp32 (cvt_pkrtz); Q A-frags from Xq16.
// 512 blocks x 4 waves: waves 0-1 = KV jobs, waves 2-3 = Q jobs (mixed-length).
__global__ __launch_bounds__(256) void proj_mfma(
    const float* __restrict__ k_in, const float* __restrict__ v_in,
    const _Float16* __restrict__ Wk16, const _Float16* __restrict__ Wv16,
    const _Float16* __restrict__ Wq16, const _Float16* __restrict__ Xq16,
    float* __restrict__ eqp, float* __restrict__ ekp, float* __restrict__ vp)
{
    const int tid = threadIdx.x;
    const int w = tid >> 6;
    const int l = tid & 63;
    const int lr = l & 15, lk = l >> 4;

    f32x4 acc0 = {0.f, 0.f, 0.f, 0.f};
    f32x4 acc1 = {0.f, 0.f, 0.f, 0.f};

    if (w < 2) {
        // ---- KV job ----
        const int j = blockIdx.x * 2 + w;          // 0..1023
        const int tensor = j >> 9;                 // 0: keys, 1: values
        const int jj = j & 511;
        const int r0 = (jj >> 2) * 16;
        const int c0 = (jj & 3) * 32;
        const float* __restrict__ X = tensor ? v_in : k_in;
        const _Float16* __restrict__ Wt = tensor ? Wv16 : Wk16;

        const float* __restrict__ Xr = X + (size_t)(r0 + lr) * 640 + lk * 8;
        const _Float16* __restrict__ W0 = Wt + (size_t)(c0 + lr) * 640 + lk * 8;
        const _Float16* __restrict__ W1 = W0 + 16 * 640;

        float4 xlo = *(const float4*)Xr;
        float4 xhi = *(const float4*)(Xr + 4);
        f16x8 b0 = *(const f16x8*)W0;
        f16x8 b1 = *(const f16x8*)W1;

        for (int s = 0; s < 20; ++s) {
            F16x8U u;
            u.h[0] = __builtin_amdgcn_cvt_pkrtz(xlo.x, xlo.y);
            u.h[1] = __builtin_amdgcn_cvt_pkrtz(xlo.z, xlo.w);
            u.h[2] = __builtin_amdgcn_cvt_pkrtz(xhi.x, xhi.y);
            u.h[3] = __builtin_amdgcn_cvt_pkrtz(xhi.z, xhi.w);
            const f16x8 a = u.v;
            const f16x8 cb0 = b0, cb1 = b1;
            if (s < 19) {                           // prefetch next step
                xlo = *(const float4*)(Xr + (s + 1) * 32);
                xhi = *(const float4*)(Xr + (s + 1) * 32 + 4);
                b0 = *(const f16x8*)(W0 + (s + 1) * 32);
                b1 = *(const f16x8*)(W1 + (s + 1) * 32);
            }
            acc0 = __builtin_amdgcn_mfma_f32_16x16x32_f16(a, cb0, acc0, 0, 0, 0);
            acc1 = __builtin_amdgcn_mfma_f32_16x16x32_f16(a, cb1, acc1, 0, 0, 0);
        }

        if (tensor == 0) {                          // ekp [b][c][t], Ek = e^{2k}
#pragma unroll
            for (int jr = 0; jr < 4; ++jr) {
                int r = r0 + lk * 4 + jr;
                int t = r >> 3, b = r & 7;
                ekp[((size_t)b * CC + c0 + lr) * TK + t] = fexp2(SCALE2L2E * acc0[jr]);
                ekp[((size_t)b * CC + c0 + 16 + lr) * TK + t] = fexp2(SCALE2L2E * acc1[jr]);
            }
        } else {                                    // vp [b][t][c]
#pragma unroll
            for (int jr = 0; jr < 4; ++jr) {
                int r = r0 + lk * 4 + jr;
                int t = r >> 3, b = r & 7;
                vp[((size_t)b * TK + t) * CC + c0 + lr] = acc0[jr];
                vp[((size_t)b * TK + t) * CC + c0 + 16 + lr] = acc1[jr];
            }
        }
    } else {
        // ---- Q job ----
        const int j = blockIdx.x * 2 + (w - 2);     // 0..1023
        const int r0 = (j >> 2) * 16;
        const int c0 = (j & 3) * 32;

        const _Float16* __restrict__ Xr = Xq16 + (size_t)(r0 + lr) * 96 + lk * 8;
        const _Float16* __restrict__ W0 = Wq16 + (size_t)(c0 + lr) * 96 + lk * 8;
        const _Float16* __restrict__ W1 = W0 + 16 * 96;

#pragma unroll
        for (int s = 0; s < 3; ++s) {
            f16x8 a = *(const f16x8*)(Xr + s * 32);
            f16x8 bb0 = *(const f16x8*)(W0 + s * 32);
            f16x8 bb1 = *(const f16x8*)(W1 + s * 32);
            acc0 = __builtin_amdgcn_mfma_f32_16x16x32_f16(a, bb0, acc0, 0, 0, 0);
            acc1 = __builtin_amdgcn_mfma_f32_16x16x32_f16(a, bb1, acc1, 0, 0, 0);
        }

#pragma unroll
        for (int jr = 0; jr < 4; ++jr) {            // eqp [b][t][c], Eq = e^{2q}
            int r = r0 + lk * 4 + jr;
            int t = r >> 3, b = r & 7;
            eqp[((size_t)b * TQ + t) * CC + c0 + lr] = fexp2(SCALE2L2E * acc0[jr]);
            eqp[((size_t)b * TQ + t) * CC + c0 + 16 + lr] = fexp2(SCALE2L2E * acc1[jr]);
        }
    }
}

// ---------------- Kernel 2: scores + softmax ----------------
// tanh(q+k) = 1 - 2/(Eq*Ek + 1): 1 TRANS + 2 VALU per element.
// Wave = 2 q-rows x 256 k (lane = k/4 via float4 from L2-resident Ek^T).
// Eq / Wvec via wave-uniform s_loads. No LDS, no barriers.
__global__ __launch_bounds__(256) void attn_kernel(const float* __restrict__ eqp,
                                                   const float* __restrict__ ekp,
                                                   const float* __restrict__ Wvec,
                                                   float* __restrict__ attn_out) {
    const int tid = threadIdx.x;
    const int lane = tid & 63;
    const int w = __builtin_amdgcn_readfirstlane(tid >> 6);
    const int b = blockIdx.y;
    const int q0 = blockIdx.x * 8 + w * 2;

    const float* __restrict__ qr0 = eqp + ((size_t)b * TQ + q0) * CC;
    const float* __restrict__ qr1 = qr0 + CC;
    const float* __restrict__ kb = ekp + (size_t)b * CC * TK + lane * 4;

    float sw = Wvec[lane] + Wvec[64 + lane];
#pragma unroll
    for (int m = 32; m >= 1; m >>= 1) sw += __shfl_xor(sw, m, 64);

    float a0[4] = {0.f, 0.f, 0.f, 0.f};
    float a1[4] = {0.f, 0.f, 0.f, 0.f};

#pragma unroll 8
    for (int c = 0; c < CC; ++c) {
        const float4 kf = *(const float4*)&kb[c * TK];
        const float eqa = qr0[c];    // s_load (uniform)
        const float eqb = qr1[c];    // s_load (uniform)
        const float wc = Wvec[c];    // s_load (uniform)
        a0[0] = fmaf(wc, frcp(fmaf(eqa, kf.x, 1.f)), a0[0]);
        a0[1] = fmaf(wc, frcp(fmaf(eqa, kf.y, 1.f)), a0[1]);
        a0[2] = fmaf(wc, frcp(fmaf(eqa, kf.z, 1.f)), a0[2]);
        a0[3] = fmaf(wc, frcp(fmaf(eqa, kf.w, 1.f)), a0[3]);
        a1[0] = fmaf(wc, frcp(fmaf(eqb, kf.x, 1.f)), a1[0]);
        a1[1] = fmaf(wc, frcp(fmaf(eqb, kf.y, 1.f)), a1[1]);
        a1[2] = fmaf(wc, frcp(fmaf(eqb, kf.z, 1.f)), a1[2]);
        a1[3] = fmaf(wc, frcp(fmaf(eqb, kf.w, 1.f)), a1[3]);
    }

    float sc0[4], sc1[4];
#pragma unroll
    for (int j = 0; j < 4; ++j) {
        sc0[j] = sw - 2.f * a0[j];
        sc1[j] = sw - 2.f * a1[j];
    }

    float m0 = fmaxf(fmaxf(sc0[0], sc0[1]), fmaxf(sc0[2], sc0[3]));
    float m1 = fmaxf(fmaxf(sc1[0], sc1[1]), fmaxf(sc1[2], sc1[3]));
#pragma unroll
    for (int m = 32; m >= 1; m >>= 1) {
        m0 = fmaxf(m0, __shfl_xor(m0, m, 64));
        m1 = fmaxf(m1, __shfl_xor(m1, m, 64));
    }
    float e0[4], e1[4], s0 = 0.f, s1 = 0.f;
#pragma unroll
    for (int j = 0; j < 4; ++j) {
        e0[j] = fexp2((sc0[j] - m0) * L2E); s0 += e0[j];
        e1[j] = fexp2((sc1[j] - m1) * L2E); s1 += e1[j];
    }
#pragma unroll
    for (int m = 32; m >= 1; m >>= 1) {
        s0 += __shfl_xor(s0, m, 64);
        s1 += __shfl_xor(s1, m, 64);
    }
    const float r0 = frcp(s0), r1 = frcp(s1);

    const float4 p0 = make_float4(e0[0] * r0, e0[1] * r0, e0[2] * r0, e0[3] * r0);
    const float4 p1 = make_float4(e1[0] * r1, e1[1] * r1, e1[2] * r1, e1[3] * r1);
    *(float4*)&attn_out[((size_t)b * TQ + q0) * TK + lane * 4] = p0;
    *(float4*)&attn_out[((size_t)b * TQ + q0 + 1) * TK + lane * 4] = p1;
}

// ---------------- Kernel 3: PV ----------------
// out[b][c][q] = sum_k p[b][q][k] * v[b][k][c].
// Thread = c, half-block = 8 q rows; p via wave-uniform s_loads, v coalesced.
__global__ __launch_bounds__(256) void pv_kernel(const float* __restrict__ attn,
                                                 const float* __restrict__ vp,
                                                 float* __restrict__ out) {
    const int tid = threadIdx.x;
    const int c = tid & 127;
    const int qh = __builtin_amdgcn_readfirstlane(tid >> 7);
    const int b = blockIdx.y;
    const int q0 = blockIdx.x * 16 + qh * 8;

    const float* __restrict__ vb = vp + (size_t)b * TK * CC + c;
    const float* __restrict__ p0 = attn + ((size_t)b * TQ + q0) * TK;   // uniform base

    float acc[8];
#pragma unroll
    for (int i = 0; i < 8; ++i) acc[i] = 0.f;

#pragma unroll 4
    for (int k = 0; k < TK; ++k) {
        const float vv = vb[k * CC];
#pragma unroll
        for (int i = 0; i < 8; ++i)
            acc[i] = fmaf(p0[i * TK + k], vv, acc[i]);   // p via s_load
    }

#pragma unroll
    for (int i = 0; i < 8; ++i)
        out[((size_t)b * CC + c) * TQ + q0 + i] = acc[i];
}

extern "C" void kernel_launch(void* const* d_in, const int* in_sizes, int n_in,
                              void* d_out, int out_size, void* d_ws, size_t ws_size,
                              hipStream_t stream) {
    const float* queries = (const float*)d_in[0];
    const float* keys    = (const float*)d_in[1];
    const float* values  = (const float*)d_in[2];
    const float* Wq      = (const float*)d_in[3];
    const float* Wk      = (const float*)d_in[4];
    const float* Wv      = (const float*)d_in[5];
    const float* Wvec    = (const float*)d_in[6];

    float* out  = (float*)d_out;                 // (8,128,512)
    float* attn = out + BB * CC * TQ;            // (8,512,256)

    float* ws = (float*)d_ws;
    float* eqp = ws;                   // [b][t][c] 4096*128 fp32, e^{2q}
    float* ekp = eqp + 4096 * CC;      // [b][c][t] 2048*128 fp32, e^{2k}
    float* vp  = ekp + 2048 * CC;      // [b][t][c] 2048*128 fp32
    _Float16* h = (_Float16*)(vp + 2048 * CC);
    _Float16* Wk16 = h;                // [128][640]
    _Float16* Wv16 = Wk16 + NWK;       // [128][640]
    _Float16* Wq16 = Wv16 + NWV;       // [128][96] (pad0)
    _Float16* Xq16 = Wq16 + NWQ;       // [4096][96] (pad0)

    convert_kernel<<<dim3(1024), 256, 0, stream>>>(
        Wk, Wv, Wq, queries, Wk16, Wv16, Wq16, Xq16);
    proj_mfma<<<dim3(512), 256, 0, stream>>>(
        keys, values, Wk16, Wv16, Wq16, Xq16, eqp, ekp, vp);
    attn_kernel<<<dim3(64, 8), 256, 0, stream>>>(eqp, ekp, Wvec, attn);
    pv_kernel<<<dim3(32, 8), 256, 0, stream>>>(attn, vp, out);
}

// Round 12
// 61.324 us; speedup vs baseline: 3.3893x; 1.0531x over previous
//
#include <hip/hip_runtime.h>

#define TQ 512
#define TK 256
#define BB 8
#define CC 128

// 2*log2(e): exp2(SCALE2L2E * x) == e^(2x)
#define SCALE2L2E 2.8853900817779268f
#define L2E 1.4426950408889634f

__device__ __forceinline__ float fexp2(float x) { return __builtin_amdgcn_exp2f(x); }
__device__ __forceinline__ float frcp(float x)  { return __builtin_amdgcn_rcpf(x); }

typedef __fp16 h16x2 __attribute__((ext_vector_type(2)));
typedef __fp16 h16x4 __attribute__((ext_vector_type(4)));
typedef __fp16 h16x8 __attribute__((ext_vector_type(8)));
typedef _Float16 f16x8 __attribute__((ext_vector_type(8)));
typedef float f32x4 __attribute__((ext_vector_type(4)));

// 8x fp32 -> f16x8 via v_cvt_pkrtz, pure register ops (no union/scratch)
__device__ __forceinline__ f16x8 pack8(float4 lo, float4 hi) {
    h16x2 a0 = __builtin_amdgcn_cvt_pkrtz(lo.x, lo.y);
    h16x2 a1 = __builtin_amdgcn_cvt_pkrtz(lo.z, lo.w);
    h16x2 a2 = __builtin_amdgcn_cvt_pkrtz(hi.x, hi.y);
    h16x2 a3 = __builtin_amdgcn_cvt_pkrtz(hi.z, hi.w);
    h16x4 p0 = __builtin_shufflevector(a0, a1, 0, 1, 2, 3);
    h16x4 p1 = __builtin_shufflevector(a2, a3, 0, 1, 2, 3);
    h16x8 r = __builtin_shufflevector(p0, p1, 0, 1, 2, 3, 4, 5, 6, 7);
    return __builtin_bit_cast(f16x8, r);
}

__device__ __forceinline__ uint2 pack4u(float4 v) {
    h16x2 lo = __builtin_amdgcn_cvt_pkrtz(v.x, v.y);
    h16x2 hi = __builtin_amdgcn_cvt_pkrtz(v.z, v.w);
    uint2 r;
    r.x = __builtin_bit_cast(unsigned int, lo);
    r.y = __builtin_bit_cast(unsigned int, hi);
    return r;
}

// ---------------- Kernel 0: fp32 -> fp16 convert, vectorized ----------------
// Wk,Wv: [128][640]. Wq: [128][80] -> [128][96] pad0. Xq: [4096][80] -> [4096][96] pad0.
// All processed as float4 -> uint2 (4 fp16) quads; 80 % 4 == 0 so pad quads are whole.
#define NWK 81920
#define NWV 81920
#define NWQ 12288
#define NXQ 393216
#define QWK 20480
#define QWV 20480
#define QWQ 3072
#define QXQ 98304
#define QTOT (QWK + QWV + QWQ + QXQ)

__global__ __launch_bounds__(256) void convert_kernel(
    const float* __restrict__ Wk, const float* __restrict__ Wv,
    const float* __restrict__ Wq, const float* __restrict__ q_in,
    uint2* __restrict__ Wk16, uint2* __restrict__ Wv16,
    uint2* __restrict__ Wq16, uint2* __restrict__ Xq16)
{
    const float4 z4 = make_float4(0.f, 0.f, 0.f, 0.f);
    for (int i = blockIdx.x * 256 + threadIdx.x; i < QTOT; i += gridDim.x * 256) {
        if (i < QWK) {
            Wk16[i] = pack4u(*(const float4*)&Wk[i * 4]);
        } else if (i < QWK + QWV) {
            int j = i - QWK;
            Wv16[j] = pack4u(*(const float4*)&Wv[j * 4]);
        } else if (i < QWK + QWV + QWQ) {
            int j = i - QWK - QWV;
            int row = j / 24, k = (j % 24) * 4;
            float4 v = (k < 80) ? *(const float4*)&Wq[row * 80 + k] : z4;
            Wq16[j] = pack4u(v);
        } else {
            int j = i - QWK - QWV - QWQ;
            int row = j / 24, k = (j % 24) * 4;
            float4 v = (k < 80) ? *(const float4*)&q_in[row * 80 + k] : z4;
            Xq16[j] = pack4u(v);
        }
    }
}

// ---------------- Kernel 1: MFMA projections v2 ----------------
// Y(rows x 128) = X(rows x K) @ W(128 x K)^T ; row r -> (t = r/8, b = r%8).
// mfma_f32_16x16x32_f16. Wave = 16 rows x 32 cols (2 c-tiles), no LDS.
// Even blocks = 4 KV waves, odd blocks = 4 Q waves (no mixed-length waves per
// block). KV: depth-2 register prefetch. V-branch writes fp16 [b][c][t] (the
// pv B-frag layout) directly.
__global__ __launch_bounds__(256) void proj_mfma(
    const float* __restrict__ k_in, const float* __restrict__ v_in,
    const _Float16* __restrict__ Wk16, const _Float16* __restrict__ Wv16,
    const _Float16* __restrict__ Wq16, const _Float16* __restrict__ Xq16,
    float* __restrict__ eqp, float* __restrict__ ekp, _Float16* __restrict__ v16)
{
    const int tid = threadIdx.x;
    const int w = tid >> 6;
    const int l = tid & 63;
    const int lr = l & 15, lk = l >> 4;
    const int id = blockIdx.x;
    const int j = (id >> 1) * 4 + w;               // job id 0..1023

    f32x4 acc0 = {0.f, 0.f, 0.f, 0.f};
    f32x4 acc1 = {0.f, 0.f, 0.f, 0.f};

    if ((id & 1) == 0) {
        // ---- KV job ----
        const int tensor = j >> 9;                 // 0: keys, 1: values
        const int jj = j & 511;
        const int r0 = (jj >> 2) * 16;
        const int c0 = (jj & 3) * 32;
        const float* __restrict__ X = tensor ? v_in : k_in;
        const _Float16* __restrict__ Wt = tensor ? Wv16 : Wk16;

        const float* __restrict__ Xr = X + (size_t)(r0 + lr) * 640 + lk * 8;
        const _Float16* __restrict__ W0 = Wt + (size_t)(c0 + lr) * 640 + lk * 8;
        const _Float16* __restrict__ W1 = W0 + 16 * 640;

        float4 xlo[2], xhi[2];
        f16x8 b0[2], b1[2];
        xlo[0] = *(const float4*)Xr;        xhi[0] = *(const float4*)(Xr + 4);
        b0[0] = *(const f16x8*)W0;          b1[0] = *(const f16x8*)W1;
        xlo[1] = *(const float4*)(Xr + 32); xhi[1] = *(const float4*)(Xr + 36);
        b0[1] = *(const f16x8*)(W0 + 32);   b1[1] = *(const f16x8*)(W1 + 32);

#pragma unroll
        for (int s = 0; s < 20; ++s) {
            const int cur = s & 1;
            const f16x8 a = pack8(xlo[cur], xhi[cur]);
            const f16x8 cb0 = b0[cur], cb1 = b1[cur];
            if (s + 2 < 20) {
                xlo[cur] = *(const float4*)(Xr + (s + 2) * 32);
                xhi[cur] = *(const float4*)(Xr + (s + 2) * 32 + 4);
                b0[cur] = *(const f16x8*)(W0 + (s + 2) * 32);
                b1[cur] = *(const f16x8*)(W1 + (s + 2) * 32);
            }
            acc0 = __builtin_amdgcn_mfma_f32_16x16x32_f16(a, cb0, acc0, 0, 0, 0);
            acc1 = __builtin_amdgcn_mfma_f32_16x16x32_f16(a, cb1, acc1, 0, 0, 0);
        }

        if (tensor == 0) {                          // ekp [b][c][t], Ek = e^{2k}
#pragma unroll
            for (int jr = 0; jr < 4; ++jr) {
                int r = r0 + lk * 4 + jr;
                int t = r >> 3, bt = r & 7;
                ekp[((size_t)bt * CC + c0 + lr) * TK + t] = fexp2(SCALE2L2E * acc0[jr]);
                ekp[((size_t)bt * CC + c0 + 16 + lr) * TK + t] = fexp2(SCALE2L2E * acc1[jr]);
            }
        } else {                                    // v16 [b][c][t] fp16
#pragma unroll
            for (int jr = 0; jr < 4; ++jr) {
                int r = r0 + lk * 4 + jr;
                int t = r >> 3, bt = r & 7;
                v16[((size_t)bt * CC + c0 + lr) * TK + t] = (_Float16)acc0[jr];
                v16[((size_t)bt * CC + c0 + 16 + lr) * TK + t] = (_Float16)acc1[jr];
            }
        }
    } else {
        // ---- Q job ----
        const int r0 = (j >> 2) * 16;
        const int c0 = (j & 3) * 32;

        const _Float16* __restrict__ Xr = Xq16 + (size_t)(r0 + lr) * 96 + lk * 8;
        const _Float16* __restrict__ W0 = Wq16 + (size_t)(c0 + lr) * 96 + lk * 8;
        const _Float16* __restrict__ W1 = W0 + 16 * 96;

#pragma unroll
        for (int s = 0; s < 3; ++s) {
            f16x8 a = *(const f16x8*)(Xr + s * 32);
            f16x8 bb0 = *(const f16x8*)(W0 + s * 32);
            f16x8 bb1 = *(const f16x8*)(W1 + s * 32);
            acc0 = __builtin_amdgcn_mfma_f32_16x16x32_f16(a, bb0, acc0, 0, 0, 0);
            acc1 = __builtin_amdgcn_mfma_f32_16x16x32_f16(a, bb1, acc1, 0, 0, 0);
        }

#pragma unroll
        for (int jr = 0; jr < 4; ++jr) {            // eqp [b][t][c], Eq = e^{2q}
            int r = r0 + lk * 4 + jr;
            int t = r >> 3, bt = r & 7;
            eqp[((size_t)bt * TQ + t) * CC + c0 + lr] = fexp2(SCALE2L2E * acc0[jr]);
            eqp[((size_t)bt * TQ + t) * CC + c0 + 16 + lr] = fexp2(SCALE2L2E * acc1[jr]);
        }
    }
}

// ---------------- Kernel 2: scores + softmax ----------------
// tanh(q+k) = 1 - 2/(Eq*Ek + 1): 1 TRANS + 2 VALU per element.
// Wave = 2 q-rows x 256 k. Uniform operands batched as float4 s_loads.
__global__ __launch_bounds__(256) void attn_kernel(const float* __restrict__ eqp,
                                                   const float* __restrict__ ekp,
                                                   const float* __restrict__ Wvec,
                                                   float* __restrict__ attn_out) {
    const int tid = threadIdx.x;
    const int lane = tid & 63;
    const int w = __builtin_amdgcn_readfirstlane(tid >> 6);
    const int b = blockIdx.y;
    const int q0 = blockIdx.x * 8 + w * 2;

    const float* __restrict__ qr0 = eqp + ((size_t)b * TQ + q0) * CC;
    const float* __restrict__ qr1 = qr0 + CC;
    const float* __restrict__ kb = ekp + (size_t)b * CC * TK + lane * 4;

    float sw = Wvec[lane] + Wvec[64 + lane];
#pragma unroll
    for (int m = 32; m >= 1; m >>= 1) sw += __shfl_xor(sw, m, 64);

    float a0[4] = {0.f, 0.f, 0.f, 0.f};
    float a1[4] = {0.f, 0.f, 0.f, 0.f};

#pragma unroll 2
    for (int c4 = 0; c4 < CC; c4 += 4) {
        const float4 wc4 = *(const float4*)&Wvec[c4];   // s_load_dwordx4
        const float4 qa4 = *(const float4*)&qr0[c4];
        const float4 qb4 = *(const float4*)&qr1[c4];
        const float wcs[4] = {wc4.x, wc4.y, wc4.z, wc4.w};
        const float qas[4] = {qa4.x, qa4.y, qa4.z, qa4.w};
        const float qbs[4] = {qb4.x, qb4.y, qb4.z, qb4.w};
#pragma unroll
        for (int u = 0; u < 4; ++u) {
            const float4 kf = *(const float4*)&kb[(c4 + u) * TK];
            a0[0] = fmaf(wcs[u], frcp(fmaf(qas[u], kf.x, 1.f)), a0[0]);
            a0[1] = fmaf(wcs[u], frcp(fmaf(qas[u], kf.y, 1.f)), a0[1]);
            a0[2] = fmaf(wcs[u], frcp(fmaf(qas[u], kf.z, 1.f)), a0[2]);
            a0[3] = fmaf(wcs[u], frcp(fmaf(qas[u], kf.w, 1.f)), a0[3]);
            a1[0] = fmaf(wcs[u], frcp(fmaf(qbs[u], kf.x, 1.f)), a1[0]);
            a1[1] = fmaf(wcs[u], frcp(fmaf(qbs[u], kf.y, 1.f)), a1[1]);
            a1[2] = fmaf(wcs[u], frcp(fmaf(qbs[u], kf.z, 1.f)), a1[2]);
            a1[3] = fmaf(wcs[u], frcp(fmaf(qbs[u], kf.w, 1.f)), a1[3]);
        }
    }

    float sc0[4], sc1[4];
#pragma unroll
    for (int j = 0; j < 4; ++j) {
        sc0[j] = sw - 2.f * a0[j];
        sc1[j] = sw - 2.f * a1[j];
    }

    float m0 = fmaxf(fmaxf(sc0[0], sc0[1]), fmaxf(sc0[2], sc0[3]));
    float m1 = fmaxf(fmaxf(sc1[0], sc1[1]), fmaxf(sc1[2], sc1[3]));
#pragma unroll
    for (int m = 32; m >= 1; m >>= 1) {
        m0 = fmaxf(m0, __shfl_xor(m0, m, 64));
        m1 = fmaxf(m1, __shfl_xor(m1, m, 64));
    }
    float e0[4], e1[4], s0 = 0.f, s1 = 0.f;
#pragma unroll
    for (int j = 0; j < 4; ++j) {
        e0[j] = fexp2((sc0[j] - m0) * L2E); s0 += e0[j];
        e1[j] = fexp2((sc1[j] - m1) * L2E); s1 += e1[j];
    }
#pragma unroll
    for (int m = 32; m >= 1; m >>= 1) {
        s0 += __shfl_xor(s0, m, 64);
        s1 += __shfl_xor(s1, m, 64);
    }
    const float r0 = frcp(s0), r1 = frcp(s1);

    const float4 p0 = make_float4(e0[0] * r0, e0[1] * r0, e0[2] * r0, e0[3] * r0);
    const float4 p1 = make_float4(e1[0] * r1, e1[1] * r1, e1[2] * r1, e1[3] * r1);
    *(float4*)&attn_out[((size_t)b * TQ + q0) * TK + lane * 4] = p0;
    *(float4*)&attn_out[((size_t)b * TQ + q0 + 1) * TK + lane * 4] = p1;
}

// ---------------- Kernel 3: PV via MFMA ----------------
// out[b][c][q] = sum_k P[b][q][k] * V[b][k][c].
// A = P (fp32 -> fp16 in-register), B = v16 [b][c][t] (B-frag native layout).
// Wave = one 16q x 16c tile, 8 k-steps. D row=q, col=c -> one float4 store/lane.
__global__ __launch_bounds__(256) void pv_mfma(const float* __restrict__ attn,
                                               const _Float16* __restrict__ v16,
                                               float* __restrict__ out) {
    const int tid = threadIdx.x;
    const int w = tid >> 6, l = tid & 63;
    const int lr = l & 15, lk = l >> 4;
    const int j = blockIdx.x * 4 + w;              // 0..2047
    const int bt = j >> 8;
    const int jj = j & 255;
    const int q0 = (jj >> 3) * 16;
    const int c0 = (jj & 7) * 16;

    const float* __restrict__ Pr = attn + ((size_t)bt * TQ + q0 + lr) * TK + lk * 8;
    const _Float16* __restrict__ Vr = v16 + ((size_t)bt * CC + c0 + lr) * TK + lk * 8;

    f32x4 acc = {0.f, 0.f, 0.f, 0.f};
#pragma unroll
    for (int s = 0; s < 8; ++s) {
        float4 plo = *(const float4*)(Pr + s * 32);
        float4 phi = *(const float4*)(Pr + s * 32 + 4);
        f16x8 a = pack8(plo, phi);
        f16x8 bv = *(const f16x8*)(Vr + s * 32);
        acc = __builtin_amdgcn_mfma_f32_16x16x32_f16(a, bv, acc, 0, 0, 0);
    }

    // D: row(q) = q0 + lk*4 + j, col(c) = c0 + lr -> 4 consecutive q = float4
    float4 o = make_float4(acc[0], acc[1], acc[2], acc[3]);
    *(float4*)&out[((size_t)bt * CC + c0 + lr) * TQ + q0 + lk * 4] = o;
}

extern "C" void kernel_launch(void* const* d_in, const int* in_sizes, int n_in,
                              void* d_out, int out_size, void* d_ws, size_t ws_size,
                              hipStream_t stream) {
    const float* queries = (const float*)d_in[0];
    const float* keys    = (const float*)d_in[1];
    const float* values  = (const float*)d_in[2];
    const float* Wq      = (const float*)d_in[3];
    const float* Wk      = (const float*)d_in[4];
    const float* Wv      = (const float*)d_in[5];
    const float* Wvec    = (const float*)d_in[6];

    float* out  = (float*)d_out;                 // (8,128,512)
    float* attn = out + BB * CC * TQ;            // (8,512,256)

    float* ws = (float*)d_ws;
    float* eqp = ws;                             // [b][t][c] 4096*128 f32, e^{2q}
    float* ekp = eqp + 4096 * CC;                // [b][c][t] 8*128*256 f32, e^{2k}
    _Float16* v16 = (_Float16*)(ekp + 2048 * CC);// [b][c][t] 8*128*256 fp16
    _Float16* Wk16 = v16 + 2048 * CC;            // [128][640]
    _Float16* Wv16 = Wk16 + NWK;                 // [128][640]
    _Float16* Wq16 = Wv16 + NWV;                 // [128][96] pad0
    _Float16* Xq16 = Wq16 + NWQ;                 // [4096][96] pad0

    convert_kernel<<<dim3(556), 256, 0, stream>>>(
        Wk, Wv, Wq, queries,
        (uint2*)Wk16, (uint2*)Wv16, (uint2*)Wq16, (uint2*)Xq16);
    proj_mfma<<<dim3(512), 256, 0, stream>>>(
        keys, values, Wk16, Wv16, Wq16, Xq16, eqp, ekp, v16);
    attn_kernel<<<dim3(64, 8), 256, 0, stream>>>(eqp, ekp, Wvec, attn);
    pv_mfma<<<dim3(512), 256, 0, stream>>>(attn, v16, out);
}

// Round 13
// 59.007 us; speedup vs baseline: 3.5223x; 1.0393x over previous
//
#include <hip/hip_runtime.h>

#define TQ 512
#define TK 256
#define BB 8
#define CC 128

// 2*log2(e): exp2(SCALE2L2E * x) == e^(2x)
#define SCALE2L2E 2.8853900817779268f
#define L2E 1.4426950408889634f

__device__ __forceinline__ float fexp2(float x) { return __builtin_amdgcn_exp2f(x); }
__device__ __forceinline__ float frcp(float x)  { return __builtin_amdgcn_rcpf(x); }

typedef __fp16 h16x2 __attribute__((ext_vector_type(2)));
typedef __fp16 h16x4 __attribute__((ext_vector_type(4)));
typedef __fp16 h16x8 __attribute__((ext_vector_type(8)));
typedef _Float16 f16x8 __attribute__((ext_vector_type(8)));
typedef float f32x4 __attribute__((ext_vector_type(4)));

// 8x fp32 -> f16x8 via v_cvt_pkrtz, pure register ops
__device__ __forceinline__ f16x8 pack8(float4 lo, float4 hi) {
    h16x2 a0 = __builtin_amdgcn_cvt_pkrtz(lo.x, lo.y);
    h16x2 a1 = __builtin_amdgcn_cvt_pkrtz(lo.z, lo.w);
    h16x2 a2 = __builtin_amdgcn_cvt_pkrtz(hi.x, hi.y);
    h16x2 a3 = __builtin_amdgcn_cvt_pkrtz(hi.z, hi.w);
    h16x4 p0 = __builtin_shufflevector(a0, a1, 0, 1, 2, 3);
    h16x4 p1 = __builtin_shufflevector(a2, a3, 0, 1, 2, 3);
    h16x8 r = __builtin_shufflevector(p0, p1, 0, 1, 2, 3, 4, 5, 6, 7);
    return __builtin_bit_cast(f16x8, r);
}

// ---------------- Kernel 0: convert + swizzle to MFMA-fragment-linear -------
// Layouts ([chunk = 16-col/row group][step][lane 64][8 halfs], 16B/lane chunks):
//   Wk16s/Wv16s: chunk(8) x step(20) -> frag (s,lk,lr,j) = W[chunk*16+lr][s*32+lk*8+j]
//   Wq16s: chunk(8) x step(3), K padded 80->96
//   Xq16s: rtile(256) x step(3), K padded
// One thread per 16B output chunk; dest coalesced, source row-gathered (small).
#define CWK 10240
#define CWV 10240
#define CWQ 1536
#define CXQ 49152
#define CTOT (CWK + CWV + CWQ + CXQ)   // 71168 = 278 * 256

__global__ __launch_bounds__(256) void convert_kernel(
    const float* __restrict__ Wk, const float* __restrict__ Wv,
    const float* __restrict__ Wq, const float* __restrict__ q_in,
    f16x8* __restrict__ Wk16s, f16x8* __restrict__ Wv16s,
    f16x8* __restrict__ Wq16s, f16x8* __restrict__ Xq16s)
{
    const int d = blockIdx.x * 256 + threadIdx.x;
    if (d >= CTOT) return;
    const f16x8 zero = {};

    if (d < CWK + CWV) {
        const int dd = (d < CWK) ? d : d - CWK;
        const float* __restrict__ W = (d < CWK) ? Wk : Wv;
        f16x8* __restrict__ dst = (d < CWK) ? Wk16s : Wv16s;
        const int chunk = dd / 1280, rem = dd % 1280;
        const int s = rem >> 6, l = rem & 63;
        const int lr = l & 15, lk = l >> 4;
        const int c = chunk * 16 + lr, k0 = s * 32 + lk * 8;
        float4 lo = *(const float4*)&W[(size_t)c * 640 + k0];
        float4 hi = *(const float4*)&W[(size_t)c * 640 + k0 + 4];
        dst[dd] = pack8(lo, hi);
    } else if (d < CWK + CWV + CWQ) {
        const int dd = d - CWK - CWV;
        const int chunk = dd / 192, rem = dd % 192;
        const int s = rem >> 6, l = rem & 63;
        const int lr = l & 15, lk = l >> 4;
        const int c = chunk * 16 + lr, k0 = s * 32 + lk * 8;
        if (k0 >= 80) { Wq16s[dd] = zero; }
        else {
            float4 lo = *(const float4*)&Wq[(size_t)c * 80 + k0];
            float4 hi = *(const float4*)&Wq[(size_t)c * 80 + k0 + 4];
            Wq16s[dd] = pack8(lo, hi);
        }
    } else {
        const int dd = d - CWK - CWV - CWQ;
        const int rtile = dd / 192, rem = dd % 192;
        const int s = rem >> 6, l = rem & 63;
        const int lr = l & 15, lk = l >> 4;
        const int r = rtile * 16 + lr, k0 = s * 32 + lk * 8;
        if (k0 >= 80) { Xq16s[dd] = zero; }
        else {
            float4 lo = *(const float4*)&q_in[(size_t)r * 80 + k0];
            float4 hi = *(const float4*)&q_in[(size_t)r * 80 + k0 + 4];
            Xq16s[dd] = pack8(lo, hi);
        }
    }
}

// ---------------- Kernel 1: MFMA projections v3 (swizzled W) ----------------
// mfma_f32_16x16x32_f16; wave = 16 rows x 32 cols (2 c-chunks). W/Xq frag
// loads fully coalesced (64 lanes x contiguous 16B). KV X fp32 loads strided
// (depth-2 prefetch). V written directly in pv's frag-linear layout.
__global__ __launch_bounds__(256) void proj_mfma(
    const float* __restrict__ k_in, const float* __restrict__ v_in,
    const _Float16* __restrict__ Wk16s, const _Float16* __restrict__ Wv16s,
    const _Float16* __restrict__ Wq16s, const _Float16* __restrict__ Xq16s,
    float* __restrict__ eqp, float* __restrict__ ekp, _Float16* __restrict__ v16s)
{
    const int tid = threadIdx.x;
    const int w = tid >> 6;
    const int l = tid & 63;
    const int lr = l & 15, lk = l >> 4;
    const int id = blockIdx.x;
    const int j = (id >> 1) * 4 + w;               // job id 0..1023

    f32x4 acc0 = {0.f, 0.f, 0.f, 0.f};
    f32x4 acc1 = {0.f, 0.f, 0.f, 0.f};

    if ((id & 1) == 0) {
        // ---- KV job ----
        const int tensor = j >> 9;                 // 0: keys, 1: values
        const int jj = j & 511;
        const int r0 = (jj >> 2) * 16;
        const int c0 = (jj & 3) * 32;
        const float* __restrict__ X = tensor ? v_in : k_in;
        const _Float16* __restrict__ Wt = tensor ? Wv16s : Wk16s;

        const float* __restrict__ Xr = X + (size_t)(r0 + lr) * 640 + lk * 8;
        const _Float16* __restrict__ B0 = Wt + (c0 >> 4) * 10240 + l * 8;
        const _Float16* __restrict__ B1 = B0 + 10240;

        float4 xlo[2], xhi[2];
        f16x8 b0[2], b1[2];
        xlo[0] = *(const float4*)Xr;        xhi[0] = *(const float4*)(Xr + 4);
        b0[0] = *(const f16x8*)B0;          b1[0] = *(const f16x8*)B1;
        xlo[1] = *(const float4*)(Xr + 32); xhi[1] = *(const float4*)(Xr + 36);
        b0[1] = *(const f16x8*)(B0 + 512);  b1[1] = *(const f16x8*)(B1 + 512);

#pragma unroll
        for (int s = 0; s < 20; ++s) {
            const int cur = s & 1;
            const f16x8 a = pack8(xlo[cur], xhi[cur]);
            const f16x8 cb0 = b0[cur], cb1 = b1[cur];
            if (s + 2 < 20) {
                xlo[cur] = *(const float4*)(Xr + (s + 2) * 32);
                xhi[cur] = *(const float4*)(Xr + (s + 2) * 32 + 4);
                b0[cur] = *(const f16x8*)(B0 + (s + 2) * 512);
                b1[cur] = *(const f16x8*)(B1 + (s + 2) * 512);
            }
            acc0 = __builtin_amdgcn_mfma_f32_16x16x32_f16(a, cb0, acc0, 0, 0, 0);
            acc1 = __builtin_amdgcn_mfma_f32_16x16x32_f16(a, cb1, acc1, 0, 0, 0);
        }

        if (tensor == 0) {                          // ekp [b][c][t], Ek = e^{2k}
#pragma unroll
            for (int jr = 0; jr < 4; ++jr) {
                int r = r0 + lk * 4 + jr;
                int t = r >> 3, bt = r & 7;
                ekp[((size_t)bt * CC + c0 + lr) * TK + t] = fexp2(SCALE2L2E * acc0[jr]);
                ekp[((size_t)bt * CC + c0 + 16 + lr) * TK + t] = fexp2(SCALE2L2E * acc1[jr]);
            }
        } else {                                    // v16s frag-linear
#pragma unroll
            for (int jr = 0; jr < 4; ++jr) {
                int r = r0 + lk * 4 + jr;
                int t = r >> 3, bt = r & 7;
                int base = bt * 32768 + (t >> 5) * 512 + ((t >> 3) & 3) * 128
                         + lr * 8 + (t & 7);
                v16s[base + (c0 >> 4) * 4096] = (_Float16)acc0[jr];
                v16s[base + ((c0 >> 4) + 1) * 4096] = (_Float16)acc1[jr];
            }
        }
    } else {
        // ---- Q job ----
        const int rtile = j >> 2;
        const int c0 = (j & 3) * 32;

        const _Float16* __restrict__ A0 = Xq16s + rtile * 1536 + l * 8;
        const _Float16* __restrict__ B0 = Wq16s + (c0 >> 4) * 1536 + l * 8;
        const _Float16* __restrict__ B1 = B0 + 1536;

#pragma unroll
        for (int s = 0; s < 3; ++s) {
            f16x8 a = *(const f16x8*)(A0 + s * 512);
            f16x8 bb0 = *(const f16x8*)(B0 + s * 512);
            f16x8 bb1 = *(const f16x8*)(B1 + s * 512);
            acc0 = __builtin_amdgcn_mfma_f32_16x16x32_f16(a, bb0, acc0, 0, 0, 0);
            acc1 = __builtin_amdgcn_mfma_f32_16x16x32_f16(a, bb1, acc1, 0, 0, 0);
        }

#pragma unroll
        for (int jr = 0; jr < 4; ++jr) {            // eqp [b][t][c], Eq = e^{2q}
            int r = rtile * 16 + lk * 4 + jr;
            int t = r >> 3, bt = r & 7;
            eqp[((size_t)bt * TQ + t) * CC + c0 + lr] = fexp2(SCALE2L2E * acc0[jr]);
            eqp[((size_t)bt * TQ + t) * CC + c0 + 16 + lr] = fexp2(SCALE2L2E * acc1[jr]);
        }
    }
}

// ---------------- Kernel 2: scores + softmax (4 q-rows/wave) ----------------
// tanh(q+k) = 1 - 2/(Eq*Ek + 1): 1 TRANS + 2 VALU per element.
// Wave = 4 q-rows x 256 k; group-of-4-c loop, next group's kf + uniform
// operands prefetched -> ~512 issue-cy of VALU per 4 in-flight loads.
__global__ __launch_bounds__(256) void attn_kernel(const float* __restrict__ eqp,
                                                   const float* __restrict__ ekp,
                                                   const float* __restrict__ Wvec,
                                                   float* __restrict__ attn_out) {
    const int tid = threadIdx.x;
    const int lane = tid & 63;
    const int w = __builtin_amdgcn_readfirstlane(tid >> 6);
    const int b = blockIdx.y;
    const int q0 = blockIdx.x * 16 + w * 4;

    const float* __restrict__ qr0 = eqp + ((size_t)b * TQ + q0) * CC;
    const float* __restrict__ qr1 = qr0 + CC;
    const float* __restrict__ qr2 = qr1 + CC;
    const float* __restrict__ qr3 = qr2 + CC;
    const float* __restrict__ kb = ekp + (size_t)b * CC * TK + lane * 4;

    float sw = Wvec[lane] + Wvec[64 + lane];
#pragma unroll
    for (int m = 32; m >= 1; m >>= 1) sw += __shfl_xor(sw, m, 64);

    float a0[4] = {0.f, 0.f, 0.f, 0.f};
    float a1[4] = {0.f, 0.f, 0.f, 0.f};
    float a2[4] = {0.f, 0.f, 0.f, 0.f};
    float a3[4] = {0.f, 0.f, 0.f, 0.f};

    float4 k0 = *(const float4*)&kb[0 * TK];
    float4 k1 = *(const float4*)&kb[1 * TK];
    float4 k2 = *(const float4*)&kb[2 * TK];
    float4 k3 = *(const float4*)&kb[3 * TK];
    float4 wv = *(const float4*)&Wvec[0];
    float4 qa = *(const float4*)&qr0[0];
    float4 qb = *(const float4*)&qr1[0];
    float4 qc = *(const float4*)&qr2[0];
    float4 qd = *(const float4*)&qr3[0];

    for (int c4 = 0; c4 < CC; c4 += 4) {
        float4 n0, n1, n2, n3, nwv, nqa, nqb, nqc, nqd;
        if (c4 + 4 < CC) {
            n0 = *(const float4*)&kb[(c4 + 4) * TK];
            n1 = *(const float4*)&kb[(c4 + 5) * TK];
            n2 = *(const float4*)&kb[(c4 + 6) * TK];
            n3 = *(const float4*)&kb[(c4 + 7) * TK];
            nwv = *(const float4*)&Wvec[c4 + 4];
            nqa = *(const float4*)&qr0[c4 + 4];
            nqb = *(const float4*)&qr1[c4 + 4];
            nqc = *(const float4*)&qr2[c4 + 4];
            nqd = *(const float4*)&qr3[c4 + 4];
        }
#define CCOMP(KF, WW, EA, EB, EC, ED)                                   \
        a0[0] = fmaf(WW, frcp(fmaf(EA, KF.x, 1.f)), a0[0]);             \
        a0[1] = fmaf(WW, frcp(fmaf(EA, KF.y, 1.f)), a0[1]);             \
        a0[2] = fmaf(WW, frcp(fmaf(EA, KF.z, 1.f)), a0[2]);             \
        a0[3] = fmaf(WW, frcp(fmaf(EA, KF.w, 1.f)), a0[3]);             \
        a1[0] = fmaf(WW, frcp(fmaf(EB, KF.x, 1.f)), a1[0]);             \
        a1[1] = fmaf(WW, frcp(fmaf(EB, KF.y, 1.f)), a1[1]);             \
        a1[2] = fmaf(WW, frcp(fmaf(EB, KF.z, 1.f)), a1[2]);             \
        a1[3] = fmaf(WW, frcp(fmaf(EB, KF.w, 1.f)), a1[3]);             \
        a2[0] = fmaf(WW, frcp(fmaf(EC, KF.x, 1.f)), a2[0]);             \
        a2[1] = fmaf(WW, frcp(fmaf(EC, KF.y, 1.f)), a2[1]);             \
        a2[2] = fmaf(WW, frcp(fmaf(EC, KF.z, 1.f)), a2[2]);             \
        a2[3] = fmaf(WW, frcp(fmaf(EC, KF.w, 1.f)), a2[3]);             \
        a3[0] = fmaf(WW, frcp(fmaf(ED, KF.x, 1.f)), a3[0]);             \
        a3[1] = fmaf(WW, frcp(fmaf(ED, KF.y, 1.f)), a3[1]);             \
        a3[2] = fmaf(WW, frcp(fmaf(ED, KF.z, 1.f)), a3[2]);             \
        a3[3] = fmaf(WW, frcp(fmaf(ED, KF.w, 1.f)), a3[3]);
        CCOMP(k0, wv.x, qa.x, qb.x, qc.x, qd.x)
        CCOMP(k1, wv.y, qa.y, qb.y, qc.y, qd.y)
        CCOMP(k2, wv.z, qa.z, qb.z, qc.z, qd.z)
        CCOMP(k3, wv.w, qa.w, qb.w, qc.w, qd.w)
#undef CCOMP
        k0 = n0; k1 = n1; k2 = n2; k3 = n3;
        wv = nwv; qa = nqa; qb = nqb; qc = nqc; qd = nqd;
    }

    float sc0[4], sc1[4], sc2[4], sc3[4];
#pragma unroll
    for (int j = 0; j < 4; ++j) {
        sc0[j] = sw - 2.f * a0[j];
        sc1[j] = sw - 2.f * a1[j];
        sc2[j] = sw - 2.f * a2[j];
        sc3[j] = sw - 2.f * a3[j];
    }

    float m0 = fmaxf(fmaxf(sc0[0], sc0[1]), fmaxf(sc0[2], sc0[3]));
    float m1 = fmaxf(fmaxf(sc1[0], sc1[1]), fmaxf(sc1[2], sc1[3]));
    float m2 = fmaxf(fmaxf(sc2[0], sc2[1]), fmaxf(sc2[2], sc2[3]));
    float m3 = fmaxf(fmaxf(sc3[0], sc3[1]), fmaxf(sc3[2], sc3[3]));
#pragma unroll
    for (int m = 32; m >= 1; m >>= 1) {
        m0 = fmaxf(m0, __shfl_xor(m0, m, 64));
        m1 = fmaxf(m1, __shfl_xor(m1, m, 64));
        m2 = fmaxf(m2, __shfl_xor(m2, m, 64));
        m3 = fmaxf(m3, __shfl_xor(m3, m, 64));
    }
    float e0[4], e1[4], e2[4], e3[4];
    float s0 = 0.f, s1 = 0.f, s2 = 0.f, s3 = 0.f;
#pragma unroll
    for (int j = 0; j < 4; ++j) {
        e0[j] = fexp2((sc0[j] - m0) * L2E); s0 += e0[j];
        e1[j] = fexp2((sc1[j] - m1) * L2E); s1 += e1[j];
        e2[j] = fexp2((sc2[j] - m2) * L2E); s2 += e2[j];
        e3[j] = fexp2((sc3[j] - m3) * L2E); s3 += e3[j];
    }
#pragma unroll
    for (int m = 32; m >= 1; m >>= 1) {
        s0 += __shfl_xor(s0, m, 64);
        s1 += __shfl_xor(s1, m, 64);
        s2 += __shfl_xor(s2, m, 64);
        s3 += __shfl_xor(s3, m, 64);
    }
    const float r0 = frcp(s0), r1 = frcp(s1), r2 = frcp(s2), r3 = frcp(s3);

    float* __restrict__ po = attn_out + ((size_t)b * TQ + q0) * TK + lane * 4;
    *(float4*)(po + 0 * TK) = make_float4(e0[0] * r0, e0[1] * r0, e0[2] * r0, e0[3] * r0);
    *(float4*)(po + 1 * TK) = make_float4(e1[0] * r1, e1[1] * r1, e1[2] * r1, e1[3] * r1);
    *(float4*)(po + 2 * TK) = make_float4(e2[0] * r2, e2[1] * r2, e2[2] * r2, e2[3] * r2);
    *(float4*)(po + 3 * TK) = make_float4(e3[0] * r3, e3[1] * r3, e3[2] * r3, e3[3] * r3);
}

// ---------------- Kernel 3: PV via MFMA (V frag-linear) ----------------
// out[b][c][q] = sum_k P[b][q][k] * V[k][c]. A = P (cvt to fp16 in-register),
// B = v16s frag-linear (coalesced 16B/lane loads).
__global__ __launch_bounds__(256) void pv_mfma(const float* __restrict__ attn,
                                               const _Float16* __restrict__ v16s,
                                               float* __restrict__ out) {
    const int tid = threadIdx.x;
    const int w = tid >> 6, l = tid & 63;
    const int lr = l & 15, lk = l >> 4;
    const int j = blockIdx.x * 4 + w;              // 0..2047
    const int bt = j >> 8;
    const int jj = j & 255;
    const int q0 = (jj >> 3) * 16;
    const int c0 = (jj & 7) * 16;

    const float* __restrict__ Pr = attn + ((size_t)bt * TQ + q0 + lr) * TK + lk * 8;
    const _Float16* __restrict__ Vr = v16s + bt * 32768 + (c0 >> 4) * 4096 + l * 8;

    f32x4 acc = {0.f, 0.f, 0.f, 0.f};
#pragma unroll
    for (int s = 0; s < 8; ++s) {
        float4 plo = *(const float4*)(Pr + s * 32);
        float4 phi = *(const float4*)(Pr + s * 32 + 4);
        f16x8 a = pack8(plo, phi);
        f16x8 bv = *(const f16x8*)(Vr + s * 512);
        acc = __builtin_amdgcn_mfma_f32_16x16x32_f16(a, bv, acc, 0, 0, 0);
    }

    float4 o = make_float4(acc[0], acc[1], acc[2], acc[3]);
    *(float4*)&out[((size_t)bt * CC + c0 + lr) * TQ + q0 + lk * 4] = o;
}

extern "C" void kernel_launch(void* const* d_in, const int* in_sizes, int n_in,
                              void* d_out, int out_size, void* d_ws, size_t ws_size,
                              hipStream_t stream) {
    const float* queries = (const float*)d_in[0];
    const float* keys    = (const float*)d_in[1];
    const float* values  = (const float*)d_in[2];
    const float* Wq      = (const float*)d_in[3];
    const float* Wk      = (const float*)d_in[4];
    const float* Wv      = (const float*)d_in[5];
    const float* Wvec    = (const float*)d_in[6];

    float* out  = (float*)d_out;                 // (8,128,512)
    float* attn = out + BB * CC * TQ;            // (8,512,256)

    float* ws = (float*)d_ws;
    float* eqp = ws;                              // [b][t][c] 4096*128 f32
    float* ekp = eqp + 4096 * CC;                 // [b][c][t] 2048*128 f32
    _Float16* v16s = (_Float16*)(ekp + 2048 * CC);// frag-linear 8*32768
    _Float16* Wk16s = v16s + 8 * 32768;           // 81920
    _Float16* Wv16s = Wk16s + 81920;              // 81920
    _Float16* Wq16s = Wv16s + 81920;              // 12288
    _Float16* Xq16s = Wq16s + 12288;              // 393216

    convert_kernel<<<dim3(278), 256, 0, stream>>>(
        Wk, Wv, Wq, queries,
        (f16x8*)Wk16s, (f16x8*)Wv16s, (f16x8*)Wq16s, (f16x8*)Xq16s);
    proj_mfma<<<dim3(512), 256, 0, stream>>>(
        keys, values, Wk16s, Wv16s, Wq16s, Xq16s, eqp, ekp, v16s);
    attn_kernel<<<dim3(32, 8), 256, 0, stream>>>(eqp, ekp, Wvec, attn);
    pv_mfma<<<dim3(512), 256, 0, stream>>>(attn, v16s, out);
}

// Round 14
// 52.834 us; speedup vs baseline: 3.9339x; 1.1168x over previous
//
#include <hip/hip_runtime.h>

#define TQ 512
#define TK 256
#define BB 8
#define CC 128

// 2*log2(e): exp2(SCALE2L2E * x) == e^(2x)
#define SCALE2L2E 2.8853900817779268f
#define L2E 1.4426950408889634f

__device__ __forceinline__ float fexp2(float x) { return __builtin_amdgcn_exp2f(x); }
__device__ __forceinline__ float frcp(float x)  { return __builtin_amdgcn_rcpf(x); }

typedef __fp16 h16x2 __attribute__((ext_vector_type(2)));
typedef __fp16 h16x4 __attribute__((ext_vector_type(4)));
typedef __fp16 h16x8 __attribute__((ext_vector_type(8)));
typedef _Float16 f16x8 __attribute__((ext_vector_type(8)));
typedef float f32x4 __attribute__((ext_vector_type(4)));

// 8x fp32 -> f16x8 via v_cvt_pkrtz, pure register ops
__device__ __forceinline__ f16x8 pack8(float4 lo, float4 hi) {
    h16x2 a0 = __builtin_amdgcn_cvt_pkrtz(lo.x, lo.y);
    h16x2 a1 = __builtin_amdgcn_cvt_pkrtz(lo.z, lo.w);
    h16x2 a2 = __builtin_amdgcn_cvt_pkrtz(hi.x, hi.y);
    h16x2 a3 = __builtin_amdgcn_cvt_pkrtz(hi.z, hi.w);
    h16x4 p0 = __builtin_shufflevector(a0, a1, 0, 1, 2, 3);
    h16x4 p1 = __builtin_shufflevector(a2, a3, 0, 1, 2, 3);
    h16x8 r = __builtin_shufflevector(p0, p1, 0, 1, 2, 3, 4, 5, 6, 7);
    return __builtin_bit_cast(f16x8, r);
}

// ---------------- Kernel 0: convert + swizzle EVERYTHING to frag-linear ----
// Frag-linear: [tile][step][lane 64][8 halfs]; frag (s,l) holds
// M[tile*16 + (l&15)][s*32 + (l>>4)*8 + j]. One thread = one 16B chunk;
// dest fully coalesced; source row-gather paid ONCE here.
//   Wk16s/Wv16s: 8 ctiles x 20 steps       (10240 chunks each)
//   Wq16s:       8 ctiles x 3 steps (pad0) (1536)
//   Xq16s:     256 rtiles x 3 steps (pad0) (49152)
//   Xk16s/Xv16s: 128 rtiles x 20 steps     (163840 each)
#define CWK 10240
#define CWV 10240
#define CWQ 1536
#define CXQ 49152
#define CXK 163840
#define CXV 163840
#define CTOT (CWK + CWV + CWQ + CXQ + CXK + CXV)   // 398848

__global__ __launch_bounds__(256) void convert_kernel(
    const float* __restrict__ Wk, const float* __restrict__ Wv,
    const float* __restrict__ Wq, const float* __restrict__ q_in,
    const float* __restrict__ k_in, const float* __restrict__ v_in,
    f16x8* __restrict__ Wk16s, f16x8* __restrict__ Wv16s,
    f16x8* __restrict__ Wq16s, f16x8* __restrict__ Xq16s,
    f16x8* __restrict__ Xk16s, f16x8* __restrict__ Xv16s)
{
    const int d = blockIdx.x * 256 + threadIdx.x;
    if (d >= CTOT) return;
    const f16x8 zero = {};

    const float* __restrict__ src;
    f16x8* __restrict__ dst;
    int dd, K;
    if (d < CWK)                         { dd = d; src = Wk; dst = Wk16s; K = 640; }
    else if (d < CWK + CWV)              { dd = d - CWK; src = Wv; dst = Wv16s; K = 640; }
    else if (d < CWK + CWV + CWQ)        { dd = d - CWK - CWV; src = Wq; dst = Wq16s; K = 80; }
    else if (d < CWK + CWV + CWQ + CXQ)  { dd = d - CWK - CWV - CWQ; src = q_in; dst = Xq16s; K = 80; }
    else if (d < CTOT - CXV)             { dd = d - CWK - CWV - CWQ - CXQ; src = k_in; dst = Xk16s; K = 640; }
    else                                 { dd = d - (CTOT - CXV); src = v_in; dst = Xv16s; K = 640; }

    const int nstep = (K == 640) ? 20 : 3;
    const int per = nstep * 64;
    const int tile = dd / per, rem = dd % per;
    const int s = rem >> 6, l = rem & 63;
    const int lr = l & 15, lk = l >> 4;
    const int r = tile * 16 + lr, k0 = s * 32 + lk * 8;
    if (K == 80 && k0 >= 80) { dst[dd] = zero; return; }
    float4 lo = *(const float4*)&src[(size_t)r * K + k0];
    float4 hi = *(const float4*)&src[(size_t)r * K + k0 + 4];
    dst[dd] = pack8(lo, hi);
}

// ---------------- Kernel 1: MFMA projections v4 (all-frag-linear) -----------
// mfma_f32_16x16x32_f16; wave = 16 rows x 32 cols (2 c-chunks). ALL loads
// coalesced 16B/lane frag-linear streams; no cvt in hot loop.
__global__ __launch_bounds__(256) void proj_mfma(
    const _Float16* __restrict__ Wk16s, const _Float16* __restrict__ Wv16s,
    const _Float16* __restrict__ Wq16s, const _Float16* __restrict__ Xq16s,
    const _Float16* __restrict__ Xk16s, const _Float16* __restrict__ Xv16s,
    float* __restrict__ eqp, float* __restrict__ ekp, _Float16* __restrict__ v16s)
{
    const int tid = threadIdx.x;
    const int w = tid >> 6;
    const int l = tid & 63;
    const int lr = l & 15, lk = l >> 4;
    const int id = blockIdx.x;
    const int j = (id >> 1) * 4 + w;               // job id 0..1023

    f32x4 acc0 = {0.f, 0.f, 0.f, 0.f};
    f32x4 acc1 = {0.f, 0.f, 0.f, 0.f};

    if ((id & 1) == 0) {
        // ---- KV job ----
        const int tensor = j >> 9;                 // 0: keys, 1: values
        const int jj = j & 511;
        const int rtile = jj >> 2;
        const int c0 = (jj & 3) * 32;
        const int r0 = rtile * 16;
        const _Float16* __restrict__ Xs = tensor ? Xv16s : Xk16s;
        const _Float16* __restrict__ Wt = tensor ? Wv16s : Wk16s;

        const _Float16* __restrict__ A0 = Xs + (size_t)rtile * 10240 + l * 8;
        const _Float16* __restrict__ B0 = Wt + (c0 >> 4) * 10240 + l * 8;
        const _Float16* __restrict__ B1 = B0 + 10240;

#pragma unroll
        for (int s = 0; s < 20; ++s) {
            f16x8 a = *(const f16x8*)(A0 + s * 512);
            f16x8 b0 = *(const f16x8*)(B0 + s * 512);
            f16x8 b1 = *(const f16x8*)(B1 + s * 512);
            acc0 = __builtin_amdgcn_mfma_f32_16x16x32_f16(a, b0, acc0, 0, 0, 0);
            acc1 = __builtin_amdgcn_mfma_f32_16x16x32_f16(a, b1, acc1, 0, 0, 0);
        }

        if (tensor == 0) {                          // ekp [b][c][t], Ek = e^{2k}
#pragma unroll
            for (int jr = 0; jr < 4; ++jr) {
                int r = r0 + lk * 4 + jr;
                int t = r >> 3, bt = r & 7;
                ekp[((size_t)bt * CC + c0 + lr) * TK + t] = fexp2(SCALE2L2E * acc0[jr]);
                ekp[((size_t)bt * CC + c0 + 16 + lr) * TK + t] = fexp2(SCALE2L2E * acc1[jr]);
            }
        } else {                                    // v16s frag-linear
#pragma unroll
            for (int jr = 0; jr < 4; ++jr) {
                int r = r0 + lk * 4 + jr;
                int t = r >> 3, bt = r & 7;
                int base = bt * 32768 + (t >> 5) * 512 + ((t >> 3) & 3) * 128
                         + lr * 8 + (t & 7);
                v16s[base + (c0 >> 4) * 4096] = (_Float16)acc0[jr];
                v16s[base + ((c0 >> 4) + 1) * 4096] = (_Float16)acc1[jr];
            }
        }
    } else {
        // ---- Q job ----
        const int rtile = j >> 2;
        const int c0 = (j & 3) * 32;

        const _Float16* __restrict__ A0 = Xq16s + (size_t)rtile * 1536 + l * 8;
        const _Float16* __restrict__ B0 = Wq16s + (c0 >> 4) * 1536 + l * 8;
        const _Float16* __restrict__ B1 = B0 + 1536;

#pragma unroll
        for (int s = 0; s < 3; ++s) {
            f16x8 a = *(const f16x8*)(A0 + s * 512);
            f16x8 bb0 = *(const f16x8*)(B0 + s * 512);
            f16x8 bb1 = *(const f16x8*)(B1 + s * 512);
            acc0 = __builtin_amdgcn_mfma_f32_16x16x32_f16(a, bb0, acc0, 0, 0, 0);
            acc1 = __builtin_amdgcn_mfma_f32_16x16x32_f16(a, bb1, acc1, 0, 0, 0);
        }

#pragma unroll
        for (int jr = 0; jr < 4; ++jr) {            // eqp [b][t][c], Eq = e^{2q}
            int r = rtile * 16 + lk * 4 + jr;
            int t = r >> 3, bt = r & 7;
            eqp[((size_t)bt * TQ + t) * CC + c0 + lr] = fexp2(SCALE2L2E * acc0[jr]);
            eqp[((size_t)bt * TQ + t) * CC + c0 + 16 + lr] = fexp2(SCALE2L2E * acc1[jr]);
        }
    }
}

// ---------------- Kernel 2: scores + softmax (4 q-rows/wave) ----------------
// tanh(q+k) = 1 - 2/(Eq*Ek + 1): 1 TRANS + 2 VALU per element.
__global__ __launch_bounds__(256) void attn_kernel(const float* __restrict__ eqp,
                                                   const float* __restrict__ ekp,
                                                   const float* __restrict__ Wvec,
                                                   float* __restrict__ attn_out) {
    const int tid = threadIdx.x;
    const int lane = tid & 63;
    const int w = __builtin_amdgcn_readfirstlane(tid >> 6);
    const int b = blockIdx.y;
    const int q0 = blockIdx.x * 16 + w * 4;

    const float* __restrict__ qr0 = eqp + ((size_t)b * TQ + q0) * CC;
    const float* __restrict__ qr1 = qr0 + CC;
    const float* __restrict__ qr2 = qr1 + CC;
    const float* __restrict__ qr3 = qr2 + CC;
    const float* __restrict__ kb = ekp + (size_t)b * CC * TK + lane * 4;

    float sw = Wvec[lane] + Wvec[64 + lane];
#pragma unroll
    for (int m = 32; m >= 1; m >>= 1) sw += __shfl_xor(sw, m, 64);

    float a0[4] = {0.f, 0.f, 0.f, 0.f};
    float a1[4] = {0.f, 0.f, 0.f, 0.f};
    float a2[4] = {0.f, 0.f, 0.f, 0.f};
    float a3[4] = {0.f, 0.f, 0.f, 0.f};

    float4 k0 = *(const float4*)&kb[0 * TK];
    float4 k1 = *(const float4*)&kb[1 * TK];
    float4 k2 = *(const float4*)&kb[2 * TK];
    float4 k3 = *(const float4*)&kb[3 * TK];
    float4 wv = *(const float4*)&Wvec[0];
    float4 qa = *(const float4*)&qr0[0];
    float4 qb = *(const float4*)&qr1[0];
    float4 qc = *(const float4*)&qr2[0];
    float4 qd = *(const float4*)&qr3[0];

    for (int c4 = 0; c4 < CC; c4 += 4) {
        float4 n0, n1, n2, n3, nwv, nqa, nqb, nqc, nqd;
        if (c4 + 4 < CC) {
            n0 = *(const float4*)&kb[(c4 + 4) * TK];
            n1 = *(const float4*)&kb[(c4 + 5) * TK];
            n2 = *(const float4*)&kb[(c4 + 6) * TK];
            n3 = *(const float4*)&kb[(c4 + 7) * TK];
            nwv = *(const float4*)&Wvec[c4 + 4];
            nqa = *(const float4*)&qr0[c4 + 4];
            nqb = *(const float4*)&qr1[c4 + 4];
            nqc = *(const float4*)&qr2[c4 + 4];
            nqd = *(const float4*)&qr3[c4 + 4];
        }
#define CCOMP(KF, WW, EA, EB, EC, ED)                                   \
        a0[0] = fmaf(WW, frcp(fmaf(EA, KF.x, 1.f)), a0[0]);             \
        a0[1] = fmaf(WW, frcp(fmaf(EA, KF.y, 1.f)), a0[1]);             \
        a0[2] = fmaf(WW, frcp(fmaf(EA, KF.z, 1.f)), a0[2]);             \
        a0[3] = fmaf(WW, frcp(fmaf(EA, KF.w, 1.f)), a0[3]);             \
        a1[0] = fmaf(WW, frcp(fmaf(EB, KF.x, 1.f)), a1[0]);             \
        a1[1] = fmaf(WW, frcp(fmaf(EB, KF.y, 1.f)), a1[1]);             \
        a1[2] = fmaf(WW, frcp(fmaf(EB, KF.z, 1.f)), a1[2]);             \
        a1[3] = fmaf(WW, frcp(fmaf(EB, KF.w, 1.f)), a1[3]);             \
        a2[0] = fmaf(WW, frcp(fmaf(EC, KF.x, 1.f)), a2[0]);             \
        a2[1] = fmaf(WW, frcp(fmaf(EC, KF.y, 1.f)), a2[1]);             \
        a2[2] = fmaf(WW, frcp(fmaf(EC, KF.z, 1.f)), a2[2]);             \
        a2[3] = fmaf(WW, frcp(fmaf(EC, KF.w, 1.f)), a2[3]);             \
        a3[0] = fmaf(WW, frcp(fmaf(ED, KF.x, 1.f)), a3[0]);             \
        a3[1] = fmaf(WW, frcp(fmaf(ED, KF.y, 1.f)), a3[1]);             \
        a3[2] = fmaf(WW, frcp(fmaf(ED, KF.z, 1.f)), a3[2]);             \
        a3[3] = fmaf(WW, frcp(fmaf(ED, KF.w, 1.f)), a3[3]);
        CCOMP(k0, wv.x, qa.x, qb.x, qc.x, qd.x)
        CCOMP(k1, wv.y, qa.y, qb.y, qc.y, qd.y)
        CCOMP(k2, wv.z, qa.z, qb.z, qc.z, qd.z)
        CCOMP(k3, wv.w, qa.w, qb.w, qc.w, qd.w)
#undef CCOMP
        k0 = n0; k1 = n1; k2 = n2; k3 = n3;
        wv = nwv; qa = nqa; qb = nqb; qc = nqc; qd = nqd;
    }

    float sc0[4], sc1[4], sc2[4], sc3[4];
#pragma unroll
    for (int j = 0; j < 4; ++j) {
        sc0[j] = sw - 2.f * a0[j];
        sc1[j] = sw - 2.f * a1[j];
        sc2[j] = sw - 2.f * a2[j];
        sc3[j] = sw - 2.f * a3[j];
    }

    float m0 = fmaxf(fmaxf(sc0[0], sc0[1]), fmaxf(sc0[2], sc0[3]));
    float m1 = fmaxf(fmaxf(sc1[0], sc1[1]), fmaxf(sc1[2], sc1[3]));
    float m2 = fmaxf(fmaxf(sc2[0], sc2[1]), fmaxf(sc2[2], sc2[3]));
    float m3 = fmaxf(fmaxf(sc3[0], sc3[1]), fmaxf(sc3[2], sc3[3]));
#pragma unroll
    for (int m = 32; m >= 1; m >>= 1) {
        m0 = fmaxf(m0, __shfl_xor(m0, m, 64));
        m1 = fmaxf(m1, __shfl_xor(m1, m, 64));
        m2 = fmaxf(m2, __shfl_xor(m2, m, 64));
        m3 = fmaxf(m3, __shfl_xor(m3, m, 64));
    }
    float e0[4], e1[4], e2[4], e3[4];
    float s0 = 0.f, s1 = 0.f, s2 = 0.f, s3 = 0.f;
#pragma unroll
    for (int j = 0; j < 4; ++j) {
        e0[j] = fexp2((sc0[j] - m0) * L2E); s0 += e0[j];
        e1[j] = fexp2((sc1[j] - m1) * L2E); s1 += e1[j];
        e2[j] = fexp2((sc2[j] - m2) * L2E); s2 += e2[j];
        e3[j] = fexp2((sc3[j] - m3) * L2E); s3 += e3[j];
    }
#pragma unroll
    for (int m = 32; m >= 1; m >>= 1) {
        s0 += __shfl_xor(s0, m, 64);
        s1 += __shfl_xor(s1, m, 64);
        s2 += __shfl_xor(s2, m, 64);
        s3 += __shfl_xor(s3, m, 64);
    }
    const float r0 = frcp(s0), r1 = frcp(s1), r2 = frcp(s2), r3 = frcp(s3);

    float* __restrict__ po = attn_out + ((size_t)b * TQ + q0) * TK + lane * 4;
    *(float4*)(po + 0 * TK) = make_float4(e0[0] * r0, e0[1] * r0, e0[2] * r0, e0[3] * r0);
    *(float4*)(po + 1 * TK) = make_float4(e1[0] * r1, e1[1] * r1, e1[2] * r1, e1[3] * r1);
    *(float4*)(po + 2 * TK) = make_float4(e2[0] * r2, e2[1] * r2, e2[2] * r2, e2[3] * r2);
    *(float4*)(po + 3 * TK) = make_float4(e3[0] * r3, e3[1] * r3, e3[2] * r3, e3[3] * r3);
}

// ---------------- Kernel 3: PV via MFMA (V frag-linear) ----------------
__global__ __launch_bounds__(256) void pv_mfma(const float* __restrict__ attn,
                                               const _Float16* __restrict__ v16s,
                                               float* __restrict__ out) {
    const int tid = threadIdx.x;
    const int w = tid >> 6, l = tid & 63;
    const int lr = l & 15, lk = l >> 4;
    const int j = blockIdx.x * 4 + w;              // 0..2047
    const int bt = j >> 8;
    const int jj = j & 255;
    const int q0 = (jj >> 3) * 16;
    const int c0 = (jj & 7) * 16;

    const float* __restrict__ Pr = attn + ((size_t)bt * TQ + q0 + lr) * TK + lk * 8;
    const _Float16* __restrict__ Vr = v16s + bt * 32768 + (c0 >> 4) * 4096 + l * 8;

    f32x4 acc = {0.f, 0.f, 0.f, 0.f};
#pragma unroll
    for (int s = 0; s < 8; ++s) {
        float4 plo = *(const float4*)(Pr + s * 32);
        float4 phi = *(const float4*)(Pr + s * 32 + 4);
        f16x8 a = pack8(plo, phi);
        f16x8 bv = *(const f16x8*)(Vr + s * 512);
        acc = __builtin_amdgcn_mfma_f32_16x16x32_f16(a, bv, acc, 0, 0, 0);
    }

    float4 o = make_float4(acc[0], acc[1], acc[2], acc[3]);
    *(float4*)&out[((size_t)bt * CC + c0 + lr) * TQ + q0 + lk * 4] = o;
}

extern "C" void kernel_launch(void* const* d_in, const int* in_sizes, int n_in,
                              void* d_out, int out_size, void* d_ws, size_t ws_size,
                              hipStream_t stream) {
    const float* queries = (const float*)d_in[0];
    const float* keys    = (const float*)d_in[1];
    const float* values  = (const float*)d_in[2];
    const float* Wq      = (const float*)d_in[3];
    const float* Wk      = (const float*)d_in[4];
    const float* Wv      = (const float*)d_in[5];
    const float* Wvec    = (const float*)d_in[6];

    float* out  = (float*)d_out;                 // (8,128,512)
    float* attn = out + BB * CC * TQ;            // (8,512,256)

    float* ws = (float*)d_ws;
    float* eqp = ws;                              // [b][t][c] 4096*128 f32
    float* ekp = eqp + 4096 * CC;                 // [b][c][t] 2048*128 f32
    _Float16* v16s = (_Float16*)(ekp + 2048 * CC);// frag-linear 8*32768
    _Float16* Wk16s = v16s + 8 * 32768;           // 81920
    _Float16* Wv16s = Wk16s + 81920;              // 81920
    _Float16* Wq16s = Wv16s + 81920;              // 12288
    _Float16* Xq16s = Wq16s + 12288;              // 393216
    _Float16* Xk16s = Xq16s + 393216;             // 1310720
    _Float16* Xv16s = Xk16s + 1310720;            // 1310720

    convert_kernel<<<dim3((CTOT + 255) / 256), 256, 0, stream>>>(
        Wk, Wv, Wq, queries, keys, values,
        (f16x8*)Wk16s, (f16x8*)Wv16s, (f16x8*)Wq16s,
        (f16x8*)Xq16s, (f16x8*)Xk16s, (f16x8*)Xv16s);
    proj_mfma<<<dim3(512), 256, 0, stream>>>(
        Wk16s, Wv16s, Wq16s, Xq16s, Xk16s, Xv16s, eqp, ekp, v16s);
    attn_kernel<<<dim3(32, 8), 256, 0, stream>>>(eqp, ekp, Wvec, attn);
    pv_mfma<<<dim3(512), 256, 0, stream>>>(attn, v16s, out);
}

// Round 16
// 47.661 us; speedup vs baseline: 4.3608x; 1.1085x over previous
//
#include <hip/hip_runtime.h>

#define TQ 512
#define TK 256
#define BB 8
#define CC 128

// 2*log2(e): exp2(SCALE2L2E * x) == e^(2x)
#define SCALE2L2E 2.8853900817779268f
#define L2E 1.4426950408889634f

__device__ __forceinline__ float fexp2(float x) { return __builtin_amdgcn_exp2f(x); }
__device__ __forceinline__ float frcp(float x)  { return __builtin_amdgcn_rcpf(x); }

typedef __fp16 h16x2 __attribute__((ext_vector_type(2)));
typedef __fp16 h16x4 __attribute__((ext_vector_type(4)));
typedef __fp16 h16x8 __attribute__((ext_vector_type(8)));
typedef _Float16 f16x8 __attribute__((ext_vector_type(8)));
typedef float f32x4 __attribute__((ext_vector_type(4)));

__device__ __forceinline__ f16x8 pack8(float4 lo, float4 hi) {
    h16x2 a0 = __builtin_amdgcn_cvt_pkrtz(lo.x, lo.y);
    h16x2 a1 = __builtin_amdgcn_cvt_pkrtz(lo.z, lo.w);
    h16x2 a2 = __builtin_amdgcn_cvt_pkrtz(hi.x, hi.y);
    h16x2 a3 = __builtin_amdgcn_cvt_pkrtz(hi.z, hi.w);
    h16x4 p0 = __builtin_shufflevector(a0, a1, 0, 1, 2, 3);
    h16x4 p1 = __builtin_shufflevector(a2, a3, 0, 1, 2, 3);
    h16x8 r = __builtin_shufflevector(p0, p1, 0, 1, 2, 3, 4, 5, 6, 7);
    return __builtin_bit_cast(f16x8, r);
}

__device__ __forceinline__ h16x4 pack4h(float4 v) {
    h16x2 lo = __builtin_amdgcn_cvt_pkrtz(v.x, v.y);
    h16x2 hi = __builtin_amdgcn_cvt_pkrtz(v.z, v.w);
    return __builtin_shufflevector(lo, hi, 0, 1, 2, 3);
}

// Frag-linear layout: [tile][step][lane 64][8 halfs]; frag (s,l) holds
// M[tile*16 + (l&15)][s*32 + (l>>4)*8 + j].
#define CWK 10240
#define CWV 10240
#define CWQ 1536
#define CXQ 49152
#define CXK 163840
#define CXV 163840
#define CTOT (CWK + CWV + CWQ + CXQ + CXK + CXV)   // 398848

// ---------------- Kernel 0: convert + swizzle to frag-linear ----------------
__global__ __launch_bounds__(256) void convert_kernel(
    const float* __restrict__ Wk, const float* __restrict__ Wv,
    const float* __restrict__ Wq, const float* __restrict__ q_in,
    const float* __restrict__ k_in, const float* __restrict__ v_in,
    f16x8* __restrict__ Wk16s, f16x8* __restrict__ Wv16s,
    f16x8* __restrict__ Wq16s, f16x8* __restrict__ Xq16s,
    f16x8* __restrict__ Xk16s, f16x8* __restrict__ Xv16s)
{
    const int d = blockIdx.x * 256 + threadIdx.x;
    if (d >= CTOT) return;
    const f16x8 zero = {};

    const float* __restrict__ src;
    f16x8* __restrict__ dst;
    int dd, K;
    if (d < CWK)                         { dd = d; src = Wk; dst = Wk16s; K = 640; }
    else if (d < CWK + CWV)              { dd = d - CWK; src = Wv; dst = Wv16s; K = 640; }
    else if (d < CWK + CWV + CWQ)        { dd = d - CWK - CWV; src = Wq; dst = Wq16s; K = 80; }
    else if (d < CWK + CWV + CWQ + CXQ)  { dd = d - CWK - CWV - CWQ; src = q_in; dst = Xq16s; K = 80; }
    else if (d < CTOT - CXV)             { dd = d - CWK - CWV - CWQ - CXQ; src = k_in; dst = Xk16s; K = 640; }
    else                                 { dd = d - (CTOT - CXV); src = v_in; dst = Xv16s; K = 640; }

    const int nstep = (K == 640) ? 20 : 3;
    const int per = nstep * 64;
    const int tile = dd / per, rem = dd % per;
    const int s = rem >> 6, l = rem & 63;
    const int lr = l & 15, lk = l >> 4;
    const int r = tile * 16 + lr, k0 = s * 32 + lk * 8;
    if (K == 80 && k0 >= 80) { dst[dd] = zero; return; }
    float4 lo = *(const float4*)&src[(size_t)r * K + k0];
    float4 hi = *(const float4*)&src[(size_t)r * K + k0 + 4];
    dst[dd] = pack8(lo, hi);
}

// ---------------- Kernel 1: MFMA projections (all-frag-linear) --------------
__global__ __launch_bounds__(256) void proj_mfma(
    const _Float16* __restrict__ Wk16s, const _Float16* __restrict__ Wv16s,
    const _Float16* __restrict__ Wq16s, const _Float16* __restrict__ Xq16s,
    const _Float16* __restrict__ Xk16s, const _Float16* __restrict__ Xv16s,
    float* __restrict__ eqp, float* __restrict__ ekp, _Float16* __restrict__ v16s)
{
    const int tid = threadIdx.x;
    const int w = tid >> 6;
    const int l = tid & 63;
    const int lr = l & 15, lk = l >> 4;
    const int id = blockIdx.x;
    const int j = (id >> 1) * 4 + w;               // job id 0..1023

    f32x4 acc0 = {0.f, 0.f, 0.f, 0.f};
    f32x4 acc1 = {0.f, 0.f, 0.f, 0.f};

    if ((id & 1) == 0) {
        // ---- KV job ----
        const int tensor = j >> 9;                 // 0: keys, 1: values
        const int jj = j & 511;
        const int rtile = jj >> 2;
        const int c0 = (jj & 3) * 32;
        const int r0 = rtile * 16;
        const _Float16* __restrict__ Xs = tensor ? Xv16s : Xk16s;
        const _Float16* __restrict__ Wt = tensor ? Wv16s : Wk16s;

        const _Float16* __restrict__ A0 = Xs + (size_t)rtile * 10240 + l * 8;
        const _Float16* __restrict__ B0 = Wt + (c0 >> 4) * 10240 + l * 8;
        const _Float16* __restrict__ B1 = B0 + 10240;

#pragma unroll
        for (int s = 0; s < 20; ++s) {
            f16x8 a = *(const f16x8*)(A0 + s * 512);
            f16x8 b0 = *(const f16x8*)(B0 + s * 512);
            f16x8 b1 = *(const f16x8*)(B1 + s * 512);
            acc0 = __builtin_amdgcn_mfma_f32_16x16x32_f16(a, b0, acc0, 0, 0, 0);
            acc1 = __builtin_amdgcn_mfma_f32_16x16x32_f16(a, b1, acc1, 0, 0, 0);
        }

        if (tensor == 0) {                          // ekp [b][c][t], Ek = e^{2k}
#pragma unroll
            for (int jr = 0; jr < 4; ++jr) {
                int r = r0 + lk * 4 + jr;
                int t = r >> 3, bt = r & 7;
                ekp[((size_t)bt * CC + c0 + lr) * TK + t] = fexp2(SCALE2L2E * acc0[jr]);
                ekp[((size_t)bt * CC + c0 + 16 + lr) * TK + t] = fexp2(SCALE2L2E * acc1[jr]);
            }
        } else {                                    // v16s frag-linear
#pragma unroll
            for (int jr = 0; jr < 4; ++jr) {
                int r = r0 + lk * 4 + jr;
                int t = r >> 3, bt = r & 7;
                int base = bt * 32768 + (t >> 5) * 512 + ((t >> 3) & 3) * 128
                         + lr * 8 + (t & 7);
                v16s[base + (c0 >> 4) * 4096] = (_Float16)acc0[jr];
                v16s[base + ((c0 >> 4) + 1) * 4096] = (_Float16)acc1[jr];
            }
        }
    } else {
        // ---- Q job ----
        const int rtile = j >> 2;
        const int c0 = (j & 3) * 32;

        const _Float16* __restrict__ A0 = Xq16s + (size_t)rtile * 1536 + l * 8;
        const _Float16* __restrict__ B0 = Wq16s + (c0 >> 4) * 1536 + l * 8;
        const _Float16* __restrict__ B1 = B0 + 1536;

#pragma unroll
        for (int s = 0; s < 3; ++s) {
            f16x8 a = *(const f16x8*)(A0 + s * 512);
            f16x8 bb0 = *(const f16x8*)(B0 + s * 512);
            f16x8 bb1 = *(const f16x8*)(B1 + s * 512);
            acc0 = __builtin_amdgcn_mfma_f32_16x16x32_f16(a, bb0, acc0, 0, 0, 0);
            acc1 = __builtin_amdgcn_mfma_f32_16x16x32_f16(a, bb1, acc1, 0, 0, 0);
        }

#pragma unroll
        for (int jr = 0; jr < 4; ++jr) {            // eqp [b][t][c], Eq = e^{2q}
            int r = rtile * 16 + lk * 4 + jr;
            int t = r >> 3, bt = r & 7;
            eqp[((size_t)bt * TQ + t) * CC + c0 + lr] = fexp2(SCALE2L2E * acc0[jr]);
            eqp[((size_t)bt * TQ + t) * CC + c0 + 16 + lr] = fexp2(SCALE2L2E * acc1[jr]);
        }
    }
}

// ---------------- Kernel 2: fused scores + softmax + PV ---------------------
// Block = (q-tile of 16 rows) x batch. Phase A: 4 waves x 4 q-rows attn
// (round-14 body). P passed via LDS (fp16, A-frag layout). Phase B: each wave
// does 2 c-tiles of 16x16 PV-MFMA; V from frag-linear v16s (L2).
__global__ __launch_bounds__(256) void attn_pv_kernel(
    const float* __restrict__ eqp, const float* __restrict__ ekp,
    const float* __restrict__ Wvec, const _Float16* __restrict__ v16s,
    float* __restrict__ attn_out, float* __restrict__ out)
{
    __shared__ _Float16 pl[16][264];

    const int tid = threadIdx.x;
    const int lane = tid & 63;
    const int w = __builtin_amdgcn_readfirstlane(tid >> 6);
    const int b = blockIdx.y;
    const int q0g = blockIdx.x * 16;
    const int q0 = q0g + w * 4;

    const float* __restrict__ qr0 = eqp + ((size_t)b * TQ + q0) * CC;
    const float* __restrict__ qr1 = qr0 + CC;
    const float* __restrict__ qr2 = qr1 + CC;
    const float* __restrict__ qr3 = qr2 + CC;
    const float* __restrict__ kb = ekp + (size_t)b * CC * TK + lane * 4;

    float sw = Wvec[lane] + Wvec[64 + lane];
#pragma unroll
    for (int m = 32; m >= 1; m >>= 1) sw += __shfl_xor(sw, m, 64);

    float a0[4] = {0.f, 0.f, 0.f, 0.f};
    float a1[4] = {0.f, 0.f, 0.f, 0.f};
    float a2[4] = {0.f, 0.f, 0.f, 0.f};
    float a3[4] = {0.f, 0.f, 0.f, 0.f};

    float4 k0 = *(const float4*)&kb[0 * TK];
    float4 k1 = *(const float4*)&kb[1 * TK];
    float4 k2 = *(const float4*)&kb[2 * TK];
    float4 k3 = *(const float4*)&kb[3 * TK];
    float4 wv = *(const float4*)&Wvec[0];
    float4 qa = *(const float4*)&qr0[0];
    float4 qb = *(const float4*)&qr1[0];
    float4 qc = *(const float4*)&qr2[0];
    float4 qd = *(const float4*)&qr3[0];

    for (int c4 = 0; c4 < CC; c4 += 4) {
        float4 n0, n1, n2, n3, nwv, nqa, nqb, nqc, nqd;
        if (c4 + 4 < CC) {
            n0 = *(const float4*)&kb[(c4 + 4) * TK];
            n1 = *(const float4*)&kb[(c4 + 5) * TK];
            n2 = *(const float4*)&kb[(c4 + 6) * TK];
            n3 = *(const float4*)&kb[(c4 + 7) * TK];
            nwv = *(const float4*)&Wvec[c4 + 4];
            nqa = *(const float4*)&qr0[c4 + 4];
            nqb = *(const float4*)&qr1[c4 + 4];
            nqc = *(const float4*)&qr2[c4 + 4];
            nqd = *(const float4*)&qr3[c4 + 4];
        }
#define CCOMP(KF, WW, EA, EB, EC, ED)                                   \
        a0[0] = fmaf(WW, frcp(fmaf(EA, KF.x, 1.f)), a0[0]);             \
        a0[1] = fmaf(WW, frcp(fmaf(EA, KF.y, 1.f)), a0[1]);             \
        a0[2] = fmaf(WW, frcp(fmaf(EA, KF.z, 1.f)), a0[2]);             \
        a0[3] = fmaf(WW, frcp(fmaf(EA, KF.w, 1.f)), a0[3]);             \
        a1[0] = fmaf(WW, frcp(fmaf(EB, KF.x, 1.f)), a1[0]);             \
        a1[1] = fmaf(WW, frcp(fmaf(EB, KF.y, 1.f)), a1[1]);             \
        a1[2] = fmaf(WW, frcp(fmaf(EB, KF.z, 1.f)), a1[2]);             \
        a1[3] = fmaf(WW, frcp(fmaf(EB, KF.w, 1.f)), a1[3]);             \
        a2[0] = fmaf(WW, frcp(fmaf(EC, KF.x, 1.f)), a2[0]);             \
        a2[1] = fmaf(WW, frcp(fmaf(EC, KF.y, 1.f)), a2[1]);             \
        a2[2] = fmaf(WW, frcp(fmaf(EC, KF.z, 1.f)), a2[2]);             \
        a2[3] = fmaf(WW, frcp(fmaf(EC, KF.w, 1.f)), a2[3]);             \
        a3[0] = fmaf(WW, frcp(fmaf(ED, KF.x, 1.f)), a3[0]);             \
        a3[1] = fmaf(WW, frcp(fmaf(ED, KF.y, 1.f)), a3[1]);             \
        a3[2] = fmaf(WW, frcp(fmaf(ED, KF.z, 1.f)), a3[2]);             \
        a3[3] = fmaf(WW, frcp(fmaf(ED, KF.w, 1.f)), a3[3]);
        CCOMP(k0, wv.x, qa.x, qb.x, qc.x, qd.x)
        CCOMP(k1, wv.y, qa.y, qb.y, qc.y, qd.y)
        CCOMP(k2, wv.z, qa.z, qb.z, qc.z, qd.z)
        CCOMP(k3, wv.w, qa.w, qb.w, qc.w, qd.w)
#undef CCOMP
        k0 = n0; k1 = n1; k2 = n2; k3 = n3;
        wv = nwv; qa = nqa; qb = nqb; qc = nqc; qd = nqd;
    }

    float sc0[4], sc1[4], sc2[4], sc3[4];
#pragma unroll
    for (int j = 0; j < 4; ++j) {
        sc0[j] = sw - 2.f * a0[j];
        sc1[j] = sw - 2.f * a1[j];
        sc2[j] = sw - 2.f * a2[j];
        sc3[j] = sw - 2.f * a3[j];
    }

    float m0 = fmaxf(fmaxf(sc0[0], sc0[1]), fmaxf(sc0[2], sc0[3]));
    float m1 = fmaxf(fmaxf(sc1[0], sc1[1]), fmaxf(sc1[2], sc1[3]));
    float m2 = fmaxf(fmaxf(sc2[0], sc2[1]), fmaxf(sc2[2], sc2[3]));
    float m3 = fmaxf(fmaxf(sc3[0], sc3[1]), fmaxf(sc3[2], sc3[3]));
#pragma unroll
    for (int m = 32; m >= 1; m >>= 1) {
        m0 = fmaxf(m0, __shfl_xor(m0, m, 64));
        m1 = fmaxf(m1, __shfl_xor(m1, m, 64));
        m2 = fmaxf(m2, __shfl_xor(m2, m, 64));
        m3 = fmaxf(m3, __shfl_xor(m3, m, 64));
    }
    float e0[4], e1[4], e2[4], e3[4];
    float s0 = 0.f, s1 = 0.f, s2 = 0.f, s3 = 0.f;
#pragma unroll
    for (int j = 0; j < 4; ++j) {
        e0[j] = fexp2((sc0[j] - m0) * L2E); s0 += e0[j];
        e1[j] = fexp2((sc1[j] - m1) * L2E); s1 += e1[j];
        e2[j] = fexp2((sc2[j] - m2) * L2E); s2 += e2[j];
        e3[j] = fexp2((sc3[j] - m3) * L2E); s3 += e3[j];
    }
#pragma unroll
    for (int m = 32; m >= 1; m >>= 1) {
        s0 += __shfl_xor(s0, m, 64);
        s1 += __shfl_xor(s1, m, 64);
        s2 += __shfl_xor(s2, m, 64);
        s3 += __shfl_xor(s3, m, 64);
    }
    const float r0 = frcp(s0), r1 = frcp(s1), r2 = frcp(s2), r3 = frcp(s3);

    const float4 p0 = make_float4(e0[0] * r0, e0[1] * r0, e0[2] * r0, e0[3] * r0);
    const float4 p1 = make_float4(e1[0] * r1, e1[1] * r1, e1[2] * r1, e1[3] * r1);
    const float4 p2 = make_float4(e2[0] * r2, e2[1] * r2, e2[2] * r2, e2[3] * r2);
    const float4 p3 = make_float4(e3[0] * r3, e3[1] * r3, e3[2] * r3, e3[3] * r3);

    float* __restrict__ po = attn_out + ((size_t)b * TQ + q0) * TK + lane * 4;
    *(float4*)(po + 0 * TK) = p0;
    *(float4*)(po + 1 * TK) = p1;
    *(float4*)(po + 2 * TK) = p2;
    *(float4*)(po + 3 * TK) = p3;

    // P -> LDS (fp16), row = local q, col = k
    *(h16x4*)&pl[w * 4 + 0][lane * 4] = pack4h(p0);
    *(h16x4*)&pl[w * 4 + 1][lane * 4] = pack4h(p1);
    *(h16x4*)&pl[w * 4 + 2][lane * 4] = pack4h(p2);
    *(h16x4*)&pl[w * 4 + 3][lane * 4] = pack4h(p3);
    __syncthreads();

    // ---- Phase B: PV. Wave w -> c-tiles w and w+4 (c0 = tile*16). ----
    const int lr = lane & 15, lk = lane >> 4;
#pragma unroll
    for (int ct = 0; ct < 2; ++ct) {
        const int ctile = w + ct * 4;
        const _Float16* __restrict__ Vr = v16s + b * 32768 + ctile * 4096 + lane * 8;
        f32x4 acc = {0.f, 0.f, 0.f, 0.f};
#pragma unroll
        for (int s = 0; s < 8; ++s) {
            f16x8 a = *(const f16x8*)&pl[lr][s * 32 + lk * 8];
            f16x8 bv = *(const f16x8*)(Vr + s * 512);
            acc = __builtin_amdgcn_mfma_f32_16x16x32_f16(a, bv, acc, 0, 0, 0);
        }
        float4 o = make_float4(acc[0], acc[1], acc[2], acc[3]);
        *(float4*)&out[((size_t)b * CC + ctile * 16 + lr) * TQ + q0g + lk * 4] = o;
    }
}

extern "C" void kernel_launch(void* const* d_in, const int* in_sizes, int n_in,
                              void* d_out, int out_size, void* d_ws, size_t ws_size,
                              hipStream_t stream) {
    const float* queries = (const float*)d_in[0];
    const float* keys    = (const float*)d_in[1];
    const float* values  = (const float*)d_in[2];
    const float* Wq      = (const float*)d_in[3];
    const float* Wk      = (const float*)d_in[4];
    const float* Wv      = (const float*)d_in[5];
    const float* Wvec    = (const float*)d_in[6];

    float* out  = (float*)d_out;                 // (8,128,512)
    float* attn = out + BB * CC * TQ;            // (8,512,256)

    float* ws = (float*)d_ws;
    float* eqp = ws;                              // [b][t][c] 4096*128 f32
    float* ekp = eqp + 4096 * CC;                 // [b][c][t] 2048*128 f32
    _Float16* v16s = (_Float16*)(ekp + 2048 * CC);// frag-linear 8*32768
    _Float16* Wk16s = v16s + 8 * 32768;           // 81920
    _Float16* Wv16s = Wk16s + 81920;              // 81920
    _Float16* Wq16s = Wv16s + 81920;              // 12288
    _Float16* Xq16s = Wq16s + 12288;              // 393216
    _Float16* Xk16s = Xq16s + 393216;             // 1310720
    _Float16* Xv16s = Xk16s + 1310720;            // 1310720

    convert_kernel<<<dim3((CTOT + 255) / 256), 256, 0, stream>>>(
        Wk, Wv, Wq, queries, keys, values,
        (f16x8*)Wk16s, (f16x8*)Wv16s, (f16x8*)Wq16s,
        (f16x8*)Xq16s, (f16x8*)Xk16s, (f16x8*)Xv16s);
    proj_mfma<<<dim3(512), 256, 0, stream>>>(
        Wk16s, Wv16s, Wq16s, Xq16s, Xk16s, Xv16s, eqp, ekp, v16s);
    attn_pv_kernel<<<dim3(32, 8), 256, 0, stream>>>(
        eqp, ekp, Wvec, v16s, attn, out);
}

// Round 17
// 41.114 us; speedup vs baseline: 5.0553x; 1.1593x over previous
//
#include <hip/hip_runtime.h>

#define TQ 512
#define TK 256
#define BB 8
#define CC 128

// 2*log2(e): exp2(SCALE2L2E * x) == e^(2x)
#define SCALE2L2E 2.8853900817779268f
#define L2E 1.4426950408889634f

__device__ __forceinline__ float fexp2(float x) { return __builtin_amdgcn_exp2f(x); }
__device__ __forceinline__ float frcp(float x)  { return __builtin_amdgcn_rcpf(x); }

typedef __fp16 h16x2 __attribute__((ext_vector_type(2)));
typedef __fp16 h16x4 __attribute__((ext_vector_type(4)));
typedef __fp16 h16x8 __attribute__((ext_vector_type(8)));
typedef _Float16 f16x8 __attribute__((ext_vector_type(8)));
typedef float f32x4 __attribute__((ext_vector_type(4)));

__device__ __forceinline__ f16x8 pack8(float4 lo, float4 hi) {
    h16x2 a0 = __builtin_amdgcn_cvt_pkrtz(lo.x, lo.y);
    h16x2 a1 = __builtin_amdgcn_cvt_pkrtz(lo.z, lo.w);
    h16x2 a2 = __builtin_amdgcn_cvt_pkrtz(hi.x, hi.y);
    h16x2 a3 = __builtin_amdgcn_cvt_pkrtz(hi.z, hi.w);
    h16x4 p0 = __builtin_shufflevector(a0, a1, 0, 1, 2, 3);
    h16x4 p1 = __builtin_shufflevector(a2, a3, 0, 1, 2, 3);
    h16x8 r = __builtin_shufflevector(p0, p1, 0, 1, 2, 3, 4, 5, 6, 7);
    return __builtin_bit_cast(f16x8, r);
}

__device__ __forceinline__ h16x4 pack4h(float4 v) {
    h16x2 lo = __builtin_amdgcn_cvt_pkrtz(v.x, v.y);
    h16x2 hi = __builtin_amdgcn_cvt_pkrtz(v.z, v.w);
    return __builtin_shufflevector(lo, hi, 0, 1, 2, 3);
}

// Frag-linear layout: [tile][step][lane 64][8 halfs]; frag (s,l) holds
// M[tile*16 + (l&15)][s*32 + (l>>4)*8 + j].
#define CWK 10240
#define CWV 10240
#define CWQ 1536
#define CXQ 49152
#define CXK 163840
#define CXV 163840
#define CTOT (CWK + CWV + CWQ + CXQ + CXK + CXV)   // 398848

// ---------------- Kernel 0: convert + swizzle to frag-linear ----------------
__global__ __launch_bounds__(256) void convert_kernel(
    const float* __restrict__ Wk, const float* __restrict__ Wv,
    const float* __restrict__ Wq, const float* __restrict__ q_in,
    const float* __restrict__ k_in, const float* __restrict__ v_in,
    f16x8* __restrict__ Wk16s, f16x8* __restrict__ Wv16s,
    f16x8* __restrict__ Wq16s, f16x8* __restrict__ Xq16s,
    f16x8* __restrict__ Xk16s, f16x8* __restrict__ Xv16s)
{
    const int d = blockIdx.x * 256 + threadIdx.x;
    if (d >= CTOT) return;
    const f16x8 zero = {};

    const float* __restrict__ src;
    f16x8* __restrict__ dst;
    int dd, K;
    if (d < CWK)                         { dd = d; src = Wk; dst = Wk16s; K = 640; }
    else if (d < CWK + CWV)              { dd = d - CWK; src = Wv; dst = Wv16s; K = 640; }
    else if (d < CWK + CWV + CWQ)        { dd = d - CWK - CWV; src = Wq; dst = Wq16s; K = 80; }
    else if (d < CWK + CWV + CWQ + CXQ)  { dd = d - CWK - CWV - CWQ; src = q_in; dst = Xq16s; K = 80; }
    else if (d < CTOT - CXV)             { dd = d - CWK - CWV - CWQ - CXQ; src = k_in; dst = Xk16s; K = 640; }
    else                                 { dd = d - (CTOT - CXV); src = v_in; dst = Xv16s; K = 640; }

    const int nstep = (K == 640) ? 20 : 3;
    const int per = nstep * 64;
    const int tile = dd / per, rem = dd % per;
    const int s = rem >> 6, l = rem & 63;
    const int lr = l & 15, lk = l >> 4;
    const int r = tile * 16 + lr, k0 = s * 32 + lk * 8;
    if (K == 80 && k0 >= 80) { dst[dd] = zero; return; }
    float4 lo = *(const float4*)&src[(size_t)r * K + k0];
    float4 hi = *(const float4*)&src[(size_t)r * K + k0 + 4];
    dst[dd] = pack8(lo, hi);
}

// ---------------- Kernel 1: MFMA projections (all-frag-linear) --------------
__global__ __launch_bounds__(256) void proj_mfma(
    const _Float16* __restrict__ Wk16s, const _Float16* __restrict__ Wv16s,
    const _Float16* __restrict__ Wq16s, const _Float16* __restrict__ Xq16s,
    const _Float16* __restrict__ Xk16s, const _Float16* __restrict__ Xv16s,
    float* __restrict__ eqp, float* __restrict__ ekp, _Float16* __restrict__ v16s)
{
    const int tid = threadIdx.x;
    const int w = tid >> 6;
    const int l = tid & 63;
    const int lr = l & 15, lk = l >> 4;
    const int id = blockIdx.x;
    const int j = (id >> 1) * 4 + w;               // job id 0..1023

    f32x4 acc0 = {0.f, 0.f, 0.f, 0.f};
    f32x4 acc1 = {0.f, 0.f, 0.f, 0.f};

    if ((id & 1) == 0) {
        // ---- KV job ----
        const int tensor = j >> 9;                 // 0: keys, 1: values
        const int jj = j & 511;
        const int rtile = jj >> 2;
        const int c0 = (jj & 3) * 32;
        const int r0 = rtile * 16;
        const _Float16* __restrict__ Xs = tensor ? Xv16s : Xk16s;
        const _Float16* __restrict__ Wt = tensor ? Wv16s : Wk16s;

        const _Float16* __restrict__ A0 = Xs + (size_t)rtile * 10240 + l * 8;
        const _Float16* __restrict__ B0 = Wt + (c0 >> 4) * 10240 + l * 8;
        const _Float16* __restrict__ B1 = B0 + 10240;

#pragma unroll
        for (int s = 0; s < 20; ++s) {
            f16x8 a = *(const f16x8*)(A0 + s * 512);
            f16x8 b0 = *(const f16x8*)(B0 + s * 512);
            f16x8 b1 = *(const f16x8*)(B1 + s * 512);
            acc0 = __builtin_amdgcn_mfma_f32_16x16x32_f16(a, b0, acc0, 0, 0, 0);
            acc1 = __builtin_amdgcn_mfma_f32_16x16x32_f16(a, b1, acc1, 0, 0, 0);
        }

        if (tensor == 0) {                          // ekp [b][c][t], Ek = e^{2k}
#pragma unroll
            for (int jr = 0; jr < 4; ++jr) {
                int r = r0 + lk * 4 + jr;
                int t = r >> 3, bt = r & 7;
                ekp[((size_t)bt * CC + c0 + lr) * TK + t] = fexp2(SCALE2L2E * acc0[jr]);
                ekp[((size_t)bt * CC + c0 + 16 + lr) * TK + t] = fexp2(SCALE2L2E * acc1[jr]);
            }
        } else {                                    // v16s frag-linear
#pragma unroll
            for (int jr = 0; jr < 4; ++jr) {
                int r = r0 + lk * 4 + jr;
                int t = r >> 3, bt = r & 7;
                int base = bt * 32768 + (t >> 5) * 512 + ((t >> 3) & 3) * 128
                         + lr * 8 + (t & 7);
                v16s[base + (c0 >> 4) * 4096] = (_Float16)acc0[jr];
                v16s[base + ((c0 >> 4) + 1) * 4096] = (_Float16)acc1[jr];
            }
        }
    } else {
        // ---- Q job ----
        const int rtile = j >> 2;
        const int c0 = (j & 3) * 32;

        const _Float16* __restrict__ A0 = Xq16s + (size_t)rtile * 1536 + l * 8;
        const _Float16* __restrict__ B0 = Wq16s + (c0 >> 4) * 1536 + l * 8;
        const _Float16* __restrict__ B1 = B0 + 1536;

#pragma unroll
        for (int s = 0; s < 3; ++s) {
            f16x8 a = *(const f16x8*)(A0 + s * 512);
            f16x8 bb0 = *(const f16x8*)(B0 + s * 512);
            f16x8 bb1 = *(const f16x8*)(B1 + s * 512);
            acc0 = __builtin_amdgcn_mfma_f32_16x16x32_f16(a, bb0, acc0, 0, 0, 0);
            acc1 = __builtin_amdgcn_mfma_f32_16x16x32_f16(a, bb1, acc1, 0, 0, 0);
        }

#pragma unroll
        for (int jr = 0; jr < 4; ++jr) {            // eqp [b][t][c], Eq = e^{2q}
            int r = rtile * 16 + lk * 4 + jr;
            int t = r >> 3, bt = r & 7;
            eqp[((size_t)bt * TQ + t) * CC + c0 + lr] = fexp2(SCALE2L2E * acc0[jr]);
            eqp[((size_t)bt * TQ + t) * CC + c0 + 16 + lr] = fexp2(SCALE2L2E * acc1[jr]);
        }
    }
}

// ---------------- Kernel 2: fused scores + softmax + PV (c-split) -----------
// Block = 512 thr (8 waves) per (16 q-rows, batch). Wave = (row-group g, c-half h):
// accumulates 64-c partial score sums; partials of h=1 pass via LDS pa (pitch 17,
// conflict-free); h=0 wave combines, softmaxes, stores attn + P (LDS fp16).
// PV: 8 waves x 1 c-tile of 16x16 MFMA. 2048 waves = 2/SIMD.
__global__ __launch_bounds__(512, 2) void attn_pv_kernel(
    const float* __restrict__ eqp, const float* __restrict__ ekp,
    const float* __restrict__ Wvec, const _Float16* __restrict__ v16s,
    float* __restrict__ attn_out, float* __restrict__ out)
{
    __shared__ float pa[4][64][17];
    __shared__ _Float16 pl[16][264];

    const int tid = threadIdx.x;
    const int lane = tid & 63;
    const int w = __builtin_amdgcn_readfirstlane(tid >> 6);   // 0..7
    const int g = w >> 1;                                     // row-group 0..3
    const int h = w & 1;                                      // c-half
    const int b = blockIdx.y;
    const int q0g = blockIdx.x * 16;
    const int q0 = q0g + g * 4;

    const float* __restrict__ qr0 = eqp + ((size_t)b * TQ + q0) * CC + h * 64;
    const float* __restrict__ qr1 = qr0 + CC;
    const float* __restrict__ qr2 = qr1 + CC;
    const float* __restrict__ qr3 = qr2 + CC;
    const float* __restrict__ kb = ekp + (size_t)b * CC * TK + (h * 64) * TK + lane * 4;
    const float* __restrict__ wvp = Wvec + h * 64;

    float sw = Wvec[lane] + Wvec[64 + lane];
#pragma unroll
    for (int m = 32; m >= 1; m >>= 1) sw += __shfl_xor(sw, m, 64);

    float a0[4] = {0.f, 0.f, 0.f, 0.f};
    float a1[4] = {0.f, 0.f, 0.f, 0.f};
    float a2[4] = {0.f, 0.f, 0.f, 0.f};
    float a3[4] = {0.f, 0.f, 0.f, 0.f};

    float4 k0 = *(const float4*)&kb[0 * TK];
    float4 k1 = *(const float4*)&kb[1 * TK];
    float4 k2 = *(const float4*)&kb[2 * TK];
    float4 k3 = *(const float4*)&kb[3 * TK];
    float4 wv = *(const float4*)&wvp[0];
    float4 qa = *(const float4*)&qr0[0];
    float4 qb = *(const float4*)&qr1[0];
    float4 qc = *(const float4*)&qr2[0];
    float4 qd = *(const float4*)&qr3[0];

    for (int c4 = 0; c4 < 64; c4 += 4) {
        float4 n0, n1, n2, n3, nwv, nqa, nqb, nqc, nqd;
        if (c4 + 4 < 64) {
            n0 = *(const float4*)&kb[(c4 + 4) * TK];
            n1 = *(const float4*)&kb[(c4 + 5) * TK];
            n2 = *(const float4*)&kb[(c4 + 6) * TK];
            n3 = *(const float4*)&kb[(c4 + 7) * TK];
            nwv = *(const float4*)&wvp[c4 + 4];
            nqa = *(const float4*)&qr0[c4 + 4];
            nqb = *(const float4*)&qr1[c4 + 4];
            nqc = *(const float4*)&qr2[c4 + 4];
            nqd = *(const float4*)&qr3[c4 + 4];
        }
#define CCOMP(KF, WW, EA, EB, EC, ED)                                   \
        a0[0] = fmaf(WW, frcp(fmaf(EA, KF.x, 1.f)), a0[0]);             \
        a0[1] = fmaf(WW, frcp(fmaf(EA, KF.y, 1.f)), a0[1]);             \
        a0[2] = fmaf(WW, frcp(fmaf(EA, KF.z, 1.f)), a0[2]);             \
        a0[3] = fmaf(WW, frcp(fmaf(EA, KF.w, 1.f)), a0[3]);             \
        a1[0] = fmaf(WW, frcp(fmaf(EB, KF.x, 1.f)), a1[0]);             \
        a1[1] = fmaf(WW, frcp(fmaf(EB, KF.y, 1.f)), a1[1]);             \
        a1[2] = fmaf(WW, frcp(fmaf(EB, KF.z, 1.f)), a1[2]);             \
        a1[3] = fmaf(WW, frcp(fmaf(EB, KF.w, 1.f)), a1[3]);             \
        a2[0] = fmaf(WW, frcp(fmaf(EC, KF.x, 1.f)), a2[0]);             \
        a2[1] = fmaf(WW, frcp(fmaf(EC, KF.y, 1.f)), a2[1]);             \
        a2[2] = fmaf(WW, frcp(fmaf(EC, KF.z, 1.f)), a2[2]);             \
        a2[3] = fmaf(WW, frcp(fmaf(EC, KF.w, 1.f)), a2[3]);             \
        a3[0] = fmaf(WW, frcp(fmaf(ED, KF.x, 1.f)), a3[0]);             \
        a3[1] = fmaf(WW, frcp(fmaf(ED, KF.y, 1.f)), a3[1]);             \
        a3[2] = fmaf(WW, frcp(fmaf(ED, KF.z, 1.f)), a3[2]);             \
        a3[3] = fmaf(WW, frcp(fmaf(ED, KF.w, 1.f)), a3[3]);
        CCOMP(k0, wv.x, qa.x, qb.x, qc.x, qd.x)
        CCOMP(k1, wv.y, qa.y, qb.y, qc.y, qd.y)
        CCOMP(k2, wv.z, qa.z, qb.z, qc.z, qd.z)
        CCOMP(k3, wv.w, qa.w, qb.w, qc.w, qd.w)
#undef CCOMP
        k0 = n0; k1 = n1; k2 = n2; k3 = n3;
        wv = nwv; qa = nqa; qb = nqb; qc = nqc; qd = nqd;
    }

    // h=1 waves publish partials (pitch 17 -> 2 lanes/bank, conflict-free)
    if (h == 1) {
#pragma unroll
        for (int jj = 0; jj < 4; ++jj) {
            pa[g][lane][jj]      = a0[jj];
            pa[g][lane][4 + jj]  = a1[jj];
            pa[g][lane][8 + jj]  = a2[jj];
            pa[g][lane][12 + jj] = a3[jj];
        }
    }
    __syncthreads();

    if (h == 0) {
#pragma unroll
        for (int jj = 0; jj < 4; ++jj) {
            a0[jj] += pa[g][lane][jj];
            a1[jj] += pa[g][lane][4 + jj];
            a2[jj] += pa[g][lane][8 + jj];
            a3[jj] += pa[g][lane][12 + jj];
        }

        float sc0[4], sc1[4], sc2[4], sc3[4];
#pragma unroll
        for (int j = 0; j < 4; ++j) {
            sc0[j] = sw - 2.f * a0[j];
            sc1[j] = sw - 2.f * a1[j];
            sc2[j] = sw - 2.f * a2[j];
            sc3[j] = sw - 2.f * a3[j];
        }

        float m0 = fmaxf(fmaxf(sc0[0], sc0[1]), fmaxf(sc0[2], sc0[3]));
        float m1 = fmaxf(fmaxf(sc1[0], sc1[1]), fmaxf(sc1[2], sc1[3]));
        float m2 = fmaxf(fmaxf(sc2[0], sc2[1]), fmaxf(sc2[2], sc2[3]));
        float m3 = fmaxf(fmaxf(sc3[0], sc3[1]), fmaxf(sc3[2], sc3[3]));
#pragma unroll
        for (int m = 32; m >= 1; m >>= 1) {
            m0 = fmaxf(m0, __shfl_xor(m0, m, 64));
            m1 = fmaxf(m1, __shfl_xor(m1, m, 64));
            m2 = fmaxf(m2, __shfl_xor(m2, m, 64));
            m3 = fmaxf(m3, __shfl_xor(m3, m, 64));
        }
        float e0[4], e1[4], e2[4], e3[4];
        float s0 = 0.f, s1 = 0.f, s2 = 0.f, s3 = 0.f;
#pragma unroll
        for (int j = 0; j < 4; ++j) {
            e0[j] = fexp2((sc0[j] - m0) * L2E); s0 += e0[j];
            e1[j] = fexp2((sc1[j] - m1) * L2E); s1 += e1[j];
            e2[j] = fexp2((sc2[j] - m2) * L2E); s2 += e2[j];
            e3[j] = fexp2((sc3[j] - m3) * L2E); s3 += e3[j];
        }
#pragma unroll
        for (int m = 32; m >= 1; m >>= 1) {
            s0 += __shfl_xor(s0, m, 64);
            s1 += __shfl_xor(s1, m, 64);
            s2 += __shfl_xor(s2, m, 64);
            s3 += __shfl_xor(s3, m, 64);
        }
        const float r0 = frcp(s0), r1 = frcp(s1), r2 = frcp(s2), r3 = frcp(s3);

        const float4 p0 = make_float4(e0[0] * r0, e0[1] * r0, e0[2] * r0, e0[3] * r0);
        const float4 p1 = make_float4(e1[0] * r1, e1[1] * r1, e1[2] * r1, e1[3] * r1);
        const float4 p2 = make_float4(e2[0] * r2, e2[1] * r2, e2[2] * r2, e2[3] * r2);
        const float4 p3 = make_float4(e3[0] * r3, e3[1] * r3, e3[2] * r3, e3[3] * r3);

        float* __restrict__ po = attn_out + ((size_t)b * TQ + q0) * TK + lane * 4;
        *(float4*)(po + 0 * TK) = p0;
        *(float4*)(po + 1 * TK) = p1;
        *(float4*)(po + 2 * TK) = p2;
        *(float4*)(po + 3 * TK) = p3;

        *(h16x4*)&pl[g * 4 + 0][lane * 4] = pack4h(p0);
        *(h16x4*)&pl[g * 4 + 1][lane * 4] = pack4h(p1);
        *(h16x4*)&pl[g * 4 + 2][lane * 4] = pack4h(p2);
        *(h16x4*)&pl[g * 4 + 3][lane * 4] = pack4h(p3);
    }
    __syncthreads();

    // ---- PV: wave w -> c-tile w (c0 = w*16) ----
    const int lr = lane & 15, lk = lane >> 4;
    const _Float16* __restrict__ Vr = v16s + b * 32768 + w * 4096 + lane * 8;
    f32x4 acc = {0.f, 0.f, 0.f, 0.f};
#pragma unroll
    for (int s = 0; s < 8; ++s) {
        f16x8 a = *(const f16x8*)&pl[lr][s * 32 + lk * 8];
        f16x8 bv = *(const f16x8*)(Vr + s * 512);
        acc = __builtin_amdgcn_mfma_f32_16x16x32_f16(a, bv, acc, 0, 0, 0);
    }
    float4 o = make_float4(acc[0], acc[1], acc[2], acc[3]);
    *(float4*)&out[((size_t)b * CC + w * 16 + lr) * TQ + q0g + lk * 4] = o;
}

extern "C" void kernel_launch(void* const* d_in, const int* in_sizes, int n_in,
                              void* d_out, int out_size, void* d_ws, size_t ws_size,
                              hipStream_t stream) {
    const float* queries = (const float*)d_in[0];
    const float* keys    = (const float*)d_in[1];
    const float* values  = (const float*)d_in[2];
    const float* Wq      = (const float*)d_in[3];
    const float* Wk      = (const float*)d_in[4];
    const float* Wv      = (const float*)d_in[5];
    const float* Wvec    = (const float*)d_in[6];

    float* out  = (float*)d_out;                 // (8,128,512)
    float* attn = out + BB * CC * TQ;            // (8,512,256)

    float* ws = (float*)d_ws;
    float* eqp = ws;                              // [b][t][c] 4096*128 f32
    float* ekp = eqp + 4096 * CC;                 // [b][c][t] 2048*128 f32
    _Float16* v16s = (_Float16*)(ekp + 2048 * CC);// frag-linear 8*32768
    _Float16* Wk16s = v16s + 8 * 32768;           // 81920
    _Float16* Wv16s = Wk16s + 81920;              // 81920
    _Float16* Wq16s = Wv16s + 81920;              // 12288
    _Float16* Xq16s = Wq16s + 12288;              // 393216
    _Float16* Xk16s = Xq16s + 393216;             // 1310720
    _Float16* Xv16s = Xk16s + 1310720;            // 1310720

    convert_kernel<<<dim3((CTOT + 255) / 256), 256, 0, stream>>>(
        Wk, Wv, Wq, queries, keys, values,
        (f16x8*)Wk16s, (f16x8*)Wv16s, (f16x8*)Wq16s,
        (f16x8*)Xq16s, (f16x8*)Xk16s, (f16x8*)Xv16s);
    proj_mfma<<<dim3(512), 256, 0, stream>>>(
        Wk16s, Wv16s, Wq16s, Xq16s, Xk16s, Xv16s, eqp, ekp, v16s);
    attn_pv_kernel<<<dim3(32, 8), 512, 0, stream>>>(
        eqp, ekp, Wvec, v16s, attn, out);
}